// Round 1
// baseline (2883.405 us; speedup 1.0000x reference)
//
#include <hip/hip_runtime.h>
#include <math.h>

namespace {

constexpr int S = 1024;     // h*w = 32*32
constexpr int C = 512;      // channels
constexpr int NBATCH = 8;
constexpr int RTOT = NBATCH * S;  // 8192 rows
constexpr int HEADS = 8;
constexpr int DH = 64;
constexpr int CAT = 3 * C;  // 1536

// ---------------- LN stats: mean + rstd per (n, s) row, coalesced along s ---
__global__ void ln_stats_kernel(const float* __restrict__ x,
                                const float* __restrict__ qx,
                                float* __restrict__ mu_x, float* __restrict__ rs_x,
                                float* __restrict__ mu_q, float* __restrict__ rs_q) {
  int r = blockIdx.x * blockDim.x + threadIdx.x;   // 0..8191
  const float* in = blockIdx.y ? qx : x;
  float* mu = blockIdx.y ? mu_q : mu_x;
  float* rs = blockIdx.y ? rs_q : rs_x;
  int n = r >> 10, si = r & (S - 1);
  const float* p = in + ((size_t)n * C) * S + si;
  float s = 0.f, sq = 0.f;
#pragma unroll 8
  for (int ch = 0; ch < C; ch++) {
    float v = p[(size_t)ch * S];
    s += v; sq += v * v;
  }
  float m = s * (1.0f / C);
  float var = sq * (1.0f / C) - m * m;
  mu[r] = m;
  rs[r] = rsqrtf(var + 1e-5f);
}

// ---------------- Tiled GEMM, optional fused LN on A, two output modes ------
// LN==1: A element (row,k) = (in[n][k][si] - mu[row]) * rs[row] * g[k] + be[k]
//        (input layout (n, c, s), row = n*1024 + si)
// LN==0: A is row-major [RTOT][C]
// OUTMODE==0: out[row*outStride + outOffset + col]  (+bias)
// OUTMODE==1: out[n][col][si]  (final NCHW transpose write, +bias)
template <int LNMODE, int OUTMODE>
__global__ void gemm_kernel(const float* __restrict__ A,
                            const float* __restrict__ mu, const float* __restrict__ rs,
                            const float* __restrict__ g, const float* __restrict__ be,
                            const float* __restrict__ W,     // [C][N] row-major
                            const float* __restrict__ bias,  // [N]
                            float* __restrict__ out, int N, int outStride, int outOffset) {
  constexpr int BM = 64, BN = 64, BK = 16;
  __shared__ float As[BK][BM];
  __shared__ float Bs[BK][BN];
  int tid = threadIdx.x;
  int col0 = blockIdx.x * BN;
  int row0 = blockIdx.y * BM;   // 64 | 1024, so block never crosses batch
  int tx = tid & 15, ty = tid >> 4;
  float acc[4][4] = {};
  int n = row0 >> 10;
  int si0 = row0 & (S - 1);

  float mrow = 0.f, rrow = 0.f;
  if (LNMODE) {
    int rr = tid & 63;
    mrow = mu[row0 + rr];
    rrow = rs[row0 + rr];
  }

  for (int k0 = 0; k0 < C; k0 += BK) {
    if (LNMODE) {
      int rr = tid & 63;      // coalesced along si
      int kq = tid >> 6;
#pragma unroll
      for (int j = 0; j < 4; j++) {
        int k = kq * 4 + j;
        float v = A[((size_t)n * C + (k0 + k)) * S + si0 + rr];
        As[k][rr] = (v - mrow) * rrow * g[k0 + k] + be[k0 + k];
      }
    } else {
      int kk = tid & 15;
      int r4 = tid >> 4;
#pragma unroll
      for (int j = 0; j < 4; j++) {
        int rr = r4 + j * 16;
        As[kk][rr] = A[(size_t)(row0 + rr) * C + k0 + kk];
      }
    }
    {
      int cc = tid & 63;      // coalesced along output cols
      int kq = tid >> 6;
#pragma unroll
      for (int j = 0; j < 4; j++) {
        int k = kq * 4 + j;
        Bs[k][cc] = W[(size_t)(k0 + k) * N + col0 + cc];
      }
    }
    __syncthreads();
#pragma unroll
    for (int kk = 0; kk < BK; kk++) {
      float4 a4 = *(const float4*)&As[kk][ty * 4];
      float4 b4 = *(const float4*)&Bs[kk][tx * 4];
      float av[4] = {a4.x, a4.y, a4.z, a4.w};
      float bv[4] = {b4.x, b4.y, b4.z, b4.w};
#pragma unroll
      for (int i = 0; i < 4; i++)
#pragma unroll
        for (int jj = 0; jj < 4; jj++)
          acc[i][jj] += av[i] * bv[jj];
    }
    __syncthreads();
  }

#pragma unroll
  for (int i = 0; i < 4; i++) {
    int row = row0 + ty * 4 + i;
#pragma unroll
    for (int jj = 0; jj < 4; jj++) {
      int col = col0 + tx * 4 + jj;
      float v = acc[i][jj] + bias[col];
      if (OUTMODE == 0) {
        out[(size_t)row * outStride + outOffset + col] = v;
      } else {
        int nn = row >> 10, ssi = row & (S - 1);
        out[((size_t)nn * C + col) * S + ssi] = v;
      }
    }
  }
}

// ---------------- Attention: one block per (n, head, 64-q-row tile) ---------
// cat row (len 1536): head h -> q at h*192, k at h*192+64, v at h*192+128
constexpr int RPP = 8;  // q-rows processed per phase

__global__ void attn_kernel(const float* __restrict__ cat_, float* __restrict__ obuf) {
  __shared__ float qs[64][68];
  __shared__ float sc[RPP][S];
  __shared__ float red[4][RPP][64];
  __shared__ float rowsum[RPP];

  int tid = threadIdx.x;
  int qtile = blockIdx.x;
  int nh = blockIdx.y;
  int n = nh >> 3, h = nh & 7;
  int q0 = qtile * 64;
  const float* base = cat_ + (size_t)n * S * CAT;
  int qoff = h * 192, koff = qoff + 64, voff = qoff + 128;

  // stage the 64 q rows for this tile
  for (int idx = tid; idx < 64 * 64; idx += 256) {
    int r = idx >> 6, d = idx & 63;
    qs[r][d] = base[(size_t)(q0 + r) * CAT + qoff + d];
  }
  __syncthreads();

  for (int phase = 0; phase < 64 / RPP; phase++) {
    // scores for RPP q-rows vs all 1024 keys
    for (int idx = tid; idx < RPP * S; idx += 256) {
      int r = idx >> 10, key = idx & (S - 1);
      const float4* krow = (const float4*)(base + (size_t)key * CAT + koff);
      const float4* qrow = (const float4*)(&qs[phase * RPP + r][0]);
      float acc = 0.f;
#pragma unroll
      for (int d4 = 0; d4 < 16; d4++) {
        float4 kk = krow[d4];
        float4 qq = qrow[d4];
        acc += qq.x * kk.x + qq.y * kk.y + qq.z * kk.z + qq.w * kk.w;
      }
      sc[r][key] = acc * 0.125f;  // / sqrt(64)
    }
    __syncthreads();
    // softmax: 32 lanes per q-row
    {
      int row = tid >> 5, lg = tid & 31;
      float m = -1e30f;
      for (int key = lg; key < S; key += 32) m = fmaxf(m, sc[row][key]);
#pragma unroll
      for (int off = 16; off; off >>= 1) m = fmaxf(m, __shfl_xor(m, off));
      float ssum = 0.f;
      for (int key = lg; key < S; key += 32) {
        float p = __expf(sc[row][key] - m);
        sc[row][key] = p;
        ssum += p;
      }
#pragma unroll
      for (int off = 16; off; off >>= 1) ssum += __shfl_xor(ssum, off);
      if (lg == 0) rowsum[row] = ssum;
    }
    __syncthreads();
    // PV: wave = one key-slice of 256, lanes = d
    {
      int d = tid & 63, ks = tid >> 6;
      float acc[RPP];
#pragma unroll
      for (int r = 0; r < RPP; r++) acc[r] = 0.f;
      const float* vb = base + voff + d;
      for (int key = ks * 256; key < ks * 256 + 256; key++) {
        float vv = vb[(size_t)key * CAT];
#pragma unroll
        for (int r = 0; r < RPP; r++) acc[r] += sc[r][key] * vv;
      }
#pragma unroll
      for (int r = 0; r < RPP; r++) red[ks][r][d] = acc[r];
    }
    __syncthreads();
    for (int idx = tid; idx < RPP * 64; idx += 256) {
      int r = idx >> 6, dd = idx & 63;
      float o = red[0][r][dd] + red[1][r][dd] + red[2][r][dd] + red[3][r][dd];
      int qr = q0 + phase * RPP + r;
      obuf[((size_t)n * S + qr) * C + h * DH + dd] = o / rowsum[r];
    }
    __syncthreads();
  }
}

}  // namespace

extern "C" void kernel_launch(void* const* d_in, const int* in_sizes, int n_in,
                              void* d_out, int out_size, void* d_ws, size_t ws_size,
                              hipStream_t stream) {
  const float* x       = (const float*)d_in[0];
  const float* qx      = (const float*)d_in[1];
  const float* q_ln_g  = (const float*)d_in[2];
  const float* q_ln_b  = (const float*)d_in[3];
  const float* q_w     = (const float*)d_in[4];
  const float* q_b     = (const float*)d_in[5];
  const float* kv_ln_g = (const float*)d_in[6];
  const float* kv_ln_b = (const float*)d_in[7];
  const float* kv_w    = (const float*)d_in[8];
  const float* kv_b    = (const float*)d_in[9];
  const float* proj_w  = (const float*)d_in[10];
  const float* proj_b  = (const float*)d_in[11];
  float* out = (float*)d_out;

  float* ws = (float*)d_ws;
  float* mu_x = ws;
  float* rs_x = ws + RTOT;
  float* mu_q = ws + 2 * RTOT;
  float* rs_q = ws + 3 * RTOT;
  float* cat_ = ws + 4 * RTOT;                    // [8192][1536] f32
  float* obuf = cat_ + (size_t)RTOT * CAT;        // [8192][512]  f32

  hipLaunchKernelGGL(ln_stats_kernel, dim3(RTOT / 256, 2), dim3(256), 0, stream,
                     x, qx, mu_x, rs_x, mu_q, rs_q);
  // q_proj -> cat[:, 0:512]
  hipLaunchKernelGGL((gemm_kernel<1, 0>), dim3(C / 64, RTOT / 64), dim3(256), 0, stream,
                     qx, mu_q, rs_q, q_ln_g, q_ln_b, q_w, q_b, cat_, C, CAT, 0);
  // kv -> cat[:, 512:1536]
  hipLaunchKernelGGL((gemm_kernel<1, 0>), dim3(2 * C / 64, RTOT / 64), dim3(256), 0, stream,
                     x, mu_x, rs_x, kv_ln_g, kv_ln_b, kv_w, kv_b, cat_, 2 * C, CAT, C);
  // attention
  hipLaunchKernelGGL(attn_kernel, dim3(S / 64, NBATCH * HEADS), dim3(256), 0, stream,
                     cat_, obuf);
  // output projection + NCHW transpose
  hipLaunchKernelGGL((gemm_kernel<0, 1>), dim3(C / 64, RTOT / 64), dim3(256), 0, stream,
                     obuf, nullptr, nullptr, nullptr, nullptr, proj_w, proj_b, out, C, 0, 0);
}

// Round 2
// 402.836 us; speedup vs baseline: 7.1578x; 7.1578x over previous
//
#include <hip/hip_runtime.h>
#include <math.h>

namespace {

constexpr int S = 1024;     // h*w = 32*32
constexpr int C = 512;      // channels
constexpr int NBATCH = 8;
constexpr int RTOT = NBATCH * S;  // 8192 rows
constexpr int HEADS = 8;
constexpr int DH = 64;

typedef __attribute__((ext_vector_type(8))) short bf16x8;
typedef __attribute__((ext_vector_type(4))) float f32x4;

__device__ inline unsigned short f2bf(float x) {
  union { float f; unsigned u; } v; v.f = x;
  unsigned r = v.u + 0x7FFF + ((v.u >> 16) & 1);
  return (unsigned short)(r >> 16);
}

// ---------------- LN stats: mean + rstd per (n, s) row, coalesced along s ---
__global__ void ln_stats_kernel(const float* __restrict__ x,
                                const float* __restrict__ qx,
                                float* __restrict__ mu_x, float* __restrict__ rs_x,
                                float* __restrict__ mu_q, float* __restrict__ rs_q) {
  int r = blockIdx.x * blockDim.x + threadIdx.x;   // 0..8191
  const float* in = blockIdx.y ? qx : x;
  float* mu = blockIdx.y ? mu_q : mu_x;
  float* rs = blockIdx.y ? rs_q : rs_x;
  int n = r >> 10, si = r & (S - 1);
  const float* p = in + ((size_t)n * C) * S + si;
  float s = 0.f, sq = 0.f;
#pragma unroll 8
  for (int ch = 0; ch < C; ch++) {
    float v = p[(size_t)ch * S];
    s += v; sq += v * v;
  }
  float m = s * (1.0f / C);
  float var = sq * (1.0f / C) - m * m;
  mu[r] = m;
  rs[r] = rsqrtf(var + 1e-5f);
}

// ---------------- Tiled GEMM, optional fused LN on A, three output modes ----
// LNMODE==1: A element (row,k) = (in[n][k][si]-mu[row])*rs[row]*g[k]+be[k]
// OUTMODE==1: out[n][col][si]  (final NCHW transpose write, +bias)
// OUTMODE==2: QKV-split bf16 writes into qout/kout/vtout per cat-channel map
template <int LNMODE, int OUTMODE>
__global__ void gemm_kernel(const float* __restrict__ A,
                            const float* __restrict__ mu, const float* __restrict__ rs,
                            const float* __restrict__ g, const float* __restrict__ be,
                            const float* __restrict__ W,     // [C][N] row-major
                            const float* __restrict__ bias,  // [N]
                            float* __restrict__ out, int N, int outOffset,
                            unsigned short* __restrict__ qout,
                            unsigned short* __restrict__ kout,
                            unsigned short* __restrict__ vtout) {
  constexpr int BM = 64, BN = 64, BK = 16;
  __shared__ float As[BK][BM];
  __shared__ float Bs[BK][BN];
  int tid = threadIdx.x;
  int col0 = blockIdx.x * BN;
  int row0 = blockIdx.y * BM;   // 64 | 1024, so block never crosses batch
  int tx = tid & 15, ty = tid >> 4;
  float acc[4][4] = {};
  int n = row0 >> 10;
  int si0 = row0 & (S - 1);

  float mrow = 0.f, rrow = 0.f;
  if (LNMODE) {
    int rr = tid & 63;
    mrow = mu[row0 + rr];
    rrow = rs[row0 + rr];
  }

  for (int k0 = 0; k0 < C; k0 += BK) {
    if (LNMODE) {
      int rr = tid & 63;      // coalesced along si
      int kq = tid >> 6;
#pragma unroll
      for (int j = 0; j < 4; j++) {
        int k = kq * 4 + j;
        float v = A[((size_t)n * C + (k0 + k)) * S + si0 + rr];
        As[k][rr] = (v - mrow) * rrow * g[k0 + k] + be[k0 + k];
      }
    } else {
      int kk = tid & 15;
      int r4 = tid >> 4;
#pragma unroll
      for (int j = 0; j < 4; j++) {
        int rr = r4 + j * 16;
        As[kk][rr] = A[(size_t)(row0 + rr) * C + k0 + kk];
      }
    }
    {
      int cc = tid & 63;      // coalesced along output cols
      int kq = tid >> 6;
#pragma unroll
      for (int j = 0; j < 4; j++) {
        int k = kq * 4 + j;
        Bs[k][cc] = W[(size_t)(k0 + k) * N + col0 + cc];
      }
    }
    __syncthreads();
#pragma unroll
    for (int kk = 0; kk < BK; kk++) {
      float4 a4 = *(const float4*)&As[kk][ty * 4];
      float4 b4 = *(const float4*)&Bs[kk][tx * 4];
      float av[4] = {a4.x, a4.y, a4.z, a4.w};
      float bv[4] = {b4.x, b4.y, b4.z, b4.w};
#pragma unroll
      for (int i = 0; i < 4; i++)
#pragma unroll
        for (int jj = 0; jj < 4; jj++)
          acc[i][jj] += av[i] * bv[jj];
    }
    __syncthreads();
  }

#pragma unroll
  for (int i = 0; i < 4; i++) {
    int row = row0 + ty * 4 + i;
#pragma unroll
    for (int jj = 0; jj < 4; jj++) {
      int col = col0 + tx * 4 + jj;
      float v = acc[i][jj] + bias[col];
      if (OUTMODE == 1) {
        int nn = row >> 10, ssi = row & (S - 1);
        out[((size_t)nn * C + col) * S + ssi] = v;
      } else {
        // QKV split: cat channel -> (head, role, d)
        int ch = outOffset + col;          // 0..1535
        int h = ch / 192;
        int role = (ch >> 6) % 3;          // 0=q 1=k 2=v
        int d = ch & 63;
        int nn = row >> 10, ssi = row & (S - 1);
        size_t nh = (size_t)(nn * HEADS + h);
        unsigned short bv16 = f2bf(v);
        if (role == 0)      qout[(nh * S + ssi) * DH + d] = bv16;
        else if (role == 1) kout[(nh * S + ssi) * DH + d] = bv16;
        else                vtout[(nh * DH + d) * S + ssi] = bv16;
      }
    }
  }
}

// ---------------- MFMA flash attention -------------------------------------
// block = (n,h) x 64 q-rows; 4 waves x 16 q-rows. KV tiles of 128 keys.
// Ks swizzled:  byte(key,d) = key*128 + ((d*2)   ^ ((key&7)<<4))
// Vs swizzled:  byte(d,key) = d*256   + ((key*2) ^ ((d&7)<<4))
// Ps swizzled (per wave): byte(q,key) = q*256 + ((key*2) ^ ((q&7)<<4))
constexpr int KVB = 128;

__global__ __launch_bounds__(256, 2) void attn_kernel(
    const unsigned short* __restrict__ Qbf, const unsigned short* __restrict__ Kbf,
    const unsigned short* __restrict__ Vtb, float* __restrict__ obuf) {
  __shared__ unsigned short Ks[KVB * DH];
  __shared__ unsigned short Vs[DH * KVB];
  __shared__ unsigned short Ps[4][16 * KVB];

  int tid = threadIdx.x;
  int wave = tid >> 6, lane = tid & 63;
  int lr = lane & 15, lg = lane >> 4;
  int qt = blockIdx.x;   // 0..15
  int nh = blockIdx.y;   // 0..63
  const unsigned short* Qg = Qbf + (size_t)nh * S * DH;
  const unsigned short* Kg = Kbf + (size_t)nh * S * DH;
  const unsigned short* Vg = Vtb + (size_t)nh * DH * S;

  // Q fragments for this wave's 16 rows (A-frag: row=lane&15, k=(lane>>4)*8+i)
  int qrow = qt * 64 + wave * 16 + lr;
  bf16x8 qf0 = *(const bf16x8*)(Qg + (size_t)qrow * DH + lg * 8);
  bf16x8 qf1 = *(const bf16x8*)(Qg + (size_t)qrow * DH + lg * 8 + 32);

  f32x4 oacc[4];
  float m_r[4], l_r[4];
#pragma unroll
  for (int dt = 0; dt < 4; dt++) oacc[dt] = (f32x4){0.f, 0.f, 0.f, 0.f};
#pragma unroll
  for (int r = 0; r < 4; r++) { m_r[r] = -1e30f; l_r[r] = 0.f; }

  char* Pw = (char*)&Ps[wave][0];

  for (int kb = 0; kb < S / KVB; kb++) {
    __syncthreads();
    // stage K tile (128 rows x 128B) and Vt tile (64 rows x 256B), swizzled
    {
      const uint4* Ksrc = (const uint4*)(Kg + (size_t)kb * KVB * DH);
#pragma unroll
      for (int it = 0; it < 4; it++) {
        int e = tid + it * 256;
        int row = e >> 3, off = e & 7;
        uint4 val = Ksrc[e];
        int b = row * 128 + ((off * 16) ^ ((row & 7) << 4));
        *(uint4*)((char*)Ks + b) = val;
      }
#pragma unroll
      for (int it = 0; it < 4; it++) {
        int e = tid + it * 256;
        int d = e >> 4, off = e & 15;
        uint4 val = *(const uint4*)((const char*)Vg + (size_t)d * 2048 + kb * 256 + off * 16);
        int b = d * 256 + ((off * 16) ^ ((d & 7) << 4));
        *(uint4*)((char*)Vs + b) = val;
      }
    }
    __syncthreads();

    // QK^T: 8 key-subtiles x 2 k-steps (d=64)
    f32x4 sc[8];
#pragma unroll
    for (int t = 0; t < 8; t++) sc[t] = (f32x4){0.f, 0.f, 0.f, 0.f};
#pragma unroll
    for (int t = 0; t < 8; t++) {
      int key = t * 16 + lr;
      int b0 = key * 128 + ((lg * 16) ^ ((key & 7) << 4));          // d = lg*8
      int b1 = key * 128 + (((lg * 8 + 32) * 2) ^ ((key & 7) << 4)); // d = lg*8+32
      bf16x8 kf0 = *(const bf16x8*)((const char*)Ks + b0);
      bf16x8 kf1 = *(const bf16x8*)((const char*)Ks + b1);
      sc[t] = __builtin_amdgcn_mfma_f32_16x16x32_bf16(qf0, kf0, sc[t], 0, 0, 0);
      sc[t] = __builtin_amdgcn_mfma_f32_16x16x32_bf16(qf1, kf1, sc[t], 0, 0, 0);
    }

    // online softmax (rows = lg*4 + r)
    float tmax[4] = {-1e30f, -1e30f, -1e30f, -1e30f};
#pragma unroll
    for (int t = 0; t < 8; t++)
#pragma unroll
      for (int r = 0; r < 4; r++) {
        sc[t][r] *= 0.125f;
        tmax[r] = fmaxf(tmax[r], sc[t][r]);
      }
#pragma unroll
    for (int off = 8; off >= 1; off >>= 1)
#pragma unroll
      for (int r = 0; r < 4; r++) tmax[r] = fmaxf(tmax[r], __shfl_xor(tmax[r], off));

    float corr[4];
#pragma unroll
    for (int r = 0; r < 4; r++) {
      float mn = fmaxf(m_r[r], tmax[r]);
      corr[r] = __expf(m_r[r] - mn);
      m_r[r] = mn;
    }

    float rsum[4] = {0.f, 0.f, 0.f, 0.f};
#pragma unroll
    for (int t = 0; t < 8; t++)
#pragma unroll
      for (int r = 0; r < 4; r++) {
        float p = __expf(sc[t][r] - m_r[r]);
        rsum[r] += p;
        int q = lg * 4 + r, key = t * 16 + lr;
        int b = q * 256 + ((key * 2) ^ ((q & 7) << 4));
        *(unsigned short*)(Pw + b) = f2bf(p);
      }
#pragma unroll
    for (int off = 8; off >= 1; off >>= 1)
#pragma unroll
      for (int r = 0; r < 4; r++) rsum[r] += __shfl_xor(rsum[r], off);
#pragma unroll
    for (int r = 0; r < 4; r++) l_r[r] = l_r[r] * corr[r] + rsum[r];
#pragma unroll
    for (int dt = 0; dt < 4; dt++)
#pragma unroll
      for (int r = 0; r < 4; r++) oacc[dt][r] *= corr[r];

    // PV: O += P(16x128) x V(128x64)
#pragma unroll
    for (int kk = 0; kk < 4; kk++) {
      int key0 = lg * 8 + kk * 32;
      int bp = lr * 256 + ((key0 * 2) ^ ((lr & 7) << 4));
      bf16x8 pf = *(const bf16x8*)((const char*)Pw + bp);
#pragma unroll
      for (int dt = 0; dt < 4; dt++) {
        int dd = dt * 16 + lr;
        int bv = dd * 256 + ((key0 * 2) ^ ((dd & 7) << 4));
        bf16x8 vf = *(const bf16x8*)((const char*)Vs + bv);
        oacc[dt] = __builtin_amdgcn_mfma_f32_16x16x32_bf16(pf, vf, oacc[dt], 0, 0, 0);
      }
    }
  }

  // epilogue: O / l -> obuf[n][s][c]
  int n = nh >> 3, h = nh & 7;
#pragma unroll
  for (int dt = 0; dt < 4; dt++)
#pragma unroll
    for (int r = 0; r < 4; r++) {
      int q = qt * 64 + wave * 16 + lg * 4 + r;
      int d = dt * 16 + lr;
      obuf[((size_t)n * S + q) * C + h * DH + d] = oacc[dt][r] / l_r[r];
    }
}

}  // namespace

extern "C" void kernel_launch(void* const* d_in, const int* in_sizes, int n_in,
                              void* d_out, int out_size, void* d_ws, size_t ws_size,
                              hipStream_t stream) {
  const float* x       = (const float*)d_in[0];
  const float* qx      = (const float*)d_in[1];
  const float* q_ln_g  = (const float*)d_in[2];
  const float* q_ln_b  = (const float*)d_in[3];
  const float* q_w     = (const float*)d_in[4];
  const float* q_b     = (const float*)d_in[5];
  const float* kv_ln_g = (const float*)d_in[6];
  const float* kv_ln_b = (const float*)d_in[7];
  const float* kv_w    = (const float*)d_in[8];
  const float* kv_b    = (const float*)d_in[9];
  const float* proj_w  = (const float*)d_in[10];
  const float* proj_b  = (const float*)d_in[11];
  float* out = (float*)d_out;

  float* ws = (float*)d_ws;
  float* mu_x = ws;
  float* rs_x = ws + RTOT;
  float* mu_q = ws + 2 * RTOT;
  float* rs_q = ws + 3 * RTOT;
  unsigned short* Qbf = (unsigned short*)(ws + 4 * RTOT);
  unsigned short* Kbf = Qbf + (size_t)NBATCH * HEADS * S * DH;   // +4M ushort
  unsigned short* Vtb = Kbf + (size_t)NBATCH * HEADS * S * DH;
  float* obuf = (float*)(Vtb + (size_t)NBATCH * HEADS * S * DH); // [8192][512] f32

  hipLaunchKernelGGL(ln_stats_kernel, dim3(RTOT / 256, 2), dim3(256), 0, stream,
                     x, qx, mu_x, rs_x, mu_q, rs_q);
  // q_proj -> cat channels [0,512)
  hipLaunchKernelGGL((gemm_kernel<1, 2>), dim3(C / 64, RTOT / 64), dim3(256), 0, stream,
                     qx, mu_q, rs_q, q_ln_g, q_ln_b, q_w, q_b, nullptr, C, 0,
                     Qbf, Kbf, Vtb);
  // kv -> cat channels [512,1536)
  hipLaunchKernelGGL((gemm_kernel<1, 2>), dim3(2 * C / 64, RTOT / 64), dim3(256), 0, stream,
                     x, mu_x, rs_x, kv_ln_g, kv_ln_b, kv_w, kv_b, nullptr, 2 * C, C,
                     Qbf, Kbf, Vtb);
  // attention
  hipLaunchKernelGGL(attn_kernel, dim3(S / 64, NBATCH * HEADS), dim3(256), 0, stream,
                     Qbf, Kbf, Vtb, obuf);
  // output projection + NCHW transpose
  hipLaunchKernelGGL((gemm_kernel<0, 1>), dim3(C / 64, RTOT / 64), dim3(256), 0, stream,
                     obuf, nullptr, nullptr, nullptr, nullptr, proj_w, proj_b, out, C, 0,
                     nullptr, nullptr, nullptr);
}

// Round 3
// 158.581 us; speedup vs baseline: 18.1825x; 2.5402x over previous
//
#include <hip/hip_runtime.h>
#include <math.h>

namespace {

constexpr int S = 1024;
constexpr int C = 512;
constexpr int NBATCH = 8;
constexpr int RTOT = NBATCH * S;  // 8192
constexpr int HEADS = 8;
constexpr int DH = 64;

typedef __attribute__((ext_vector_type(8))) short bf16x8;
typedef __attribute__((ext_vector_type(4))) float f32x4;
typedef unsigned short u16;
typedef unsigned int u32;

__device__ __forceinline__ u16 f2bf(float x) {
  union { float f; u32 u; } v; v.f = x;
  u32 r = v.u + 0x7FFF + ((v.u >> 16) & 1);
  return (u16)(r >> 16);
}
__device__ __forceinline__ float bf2f(u16 b) {
  union { u32 u; float f; } v; v.u = (u32)b << 16; return v.f;
}
__device__ __forceinline__ void gl_lds16(const void* g, void* l) {
  auto gp = (const __attribute__((address_space(1))) u32*)g;
  auto lp = (__attribute__((address_space(3))) u32*)l;
  __builtin_amdgcn_global_load_lds(gp, lp, 16, 0, 0);
}

// ---------------- LN stats: 256 blocks, 4 c-quarters per block --------------
__global__ void ln_stats_kernel(const float* __restrict__ x,
                                const float* __restrict__ qx,
                                float* __restrict__ mu_x, float* __restrict__ rs_x,
                                float* __restrict__ mu_q, float* __restrict__ rs_q) {
  __shared__ float Ssum[4][64], Ssq[4][64];
  int t = threadIdx.x;
  int r0 = blockIdx.x * 64;
  const float* in = blockIdx.y ? qx : x;
  float* mu = blockIdx.y ? mu_q : mu_x;
  float* rs = blockIdx.y ? rs_q : rs_x;
  int n = r0 >> 10, siL = (r0 & (S - 1)) + (t & 63);
  const float* p = in + ((size_t)n * C + (t >> 6) * 128) * S + siL;
  float s = 0.f, sq = 0.f;
#pragma unroll 8
  for (int c = 0; c < 128; c++) { float v = p[(size_t)c * S]; s += v; sq += v * v; }
  Ssum[t >> 6][t & 63] = s; Ssq[t >> 6][t & 63] = sq;
  __syncthreads();
  if (t < 64) {
    float ss = Ssum[0][t] + Ssum[1][t] + Ssum[2][t] + Ssum[3][t];
    float q2 = Ssq[0][t] + Ssq[1][t] + Ssq[2][t] + Ssq[3][t];
    float m = ss * (1.0f / C);
    float var = q2 * (1.0f / C) - m * m;
    mu[r0 + t] = m;
    rs[r0 + t] = rsqrtf(var + 1e-5f);
  }
}

// ---------------- LN apply + NCHW->(row,c) transpose + bf16 -----------------
__global__ void ln_apply_tr(const float* __restrict__ x, const float* __restrict__ qx,
                            const float* __restrict__ mu_x, const float* __restrict__ rs_x,
                            const float* __restrict__ mu_q, const float* __restrict__ rs_q,
                            const float* __restrict__ gx, const float* __restrict__ bx,
                            const float* __restrict__ gq, const float* __restrict__ bq,
                            u16* __restrict__ Xkv, u16* __restrict__ Xq) {
  __shared__ float T[64][65];
  int t = threadIdx.x;
  int si0 = blockIdx.x * 64, c0 = blockIdx.y * 64;
  int isq = blockIdx.z & 1, n = blockIdx.z >> 1;
  const float* in = isq ? qx : x;
  const float* mu = isq ? mu_q : mu_x;
  const float* rs = isq ? rs_q : rs_x;
  const float* g = isq ? gq : gx;
  const float* be = isq ? bq : bx;
  u16* out = isq ? Xq : Xkv;

  int sl4 = (t & 15) * 4, cl = t >> 4;
  float4 mu4 = *(const float4*)&mu[n * S + si0 + sl4];
  float4 rs4 = *(const float4*)&rs[n * S + si0 + sl4];
#pragma unroll
  for (int i = 0; i < 4; i++) {
    int c = c0 + cl + i * 16;
    float4 v = *(const float4*)&in[((size_t)n * C + c) * S + si0 + sl4];
    float gg = g[c], bb = be[c];
    T[sl4 + 0][cl + i * 16] = (v.x - mu4.x) * rs4.x * gg + bb;
    T[sl4 + 1][cl + i * 16] = (v.y - mu4.y) * rs4.y * gg + bb;
    T[sl4 + 2][cl + i * 16] = (v.z - mu4.z) * rs4.z * gg + bb;
    T[sl4 + 3][cl + i * 16] = (v.w - mu4.w) * rs4.w * gg + bb;
  }
  __syncthreads();
#pragma unroll
  for (int p = 0; p < 2; p++) {
    int sl = (t >> 3) + p * 32, c8 = (t & 7) * 8;
    u16 pk[8];
#pragma unroll
    for (int j = 0; j < 8; j++) pk[j] = f2bf(T[sl][c8 + j]);
    *(uint4*)&out[((size_t)(n * S + si0 + sl)) * C + c0 + c8] = *(const uint4*)pk;
  }
}

// ---------------- Weight prep: W[k][col] -> Wt[col][k] bf16 (+split for proj)
__global__ void prep_w(const float* __restrict__ qw, const float* __restrict__ kvw,
                       const float* __restrict__ pw,
                       u16* __restrict__ Wtq, u16* __restrict__ Wtkv,
                       u16* __restrict__ Wph, u16* __restrict__ Wpl) {
  int z = blockIdx.z;
  int N = (z == 1) ? 1024 : 512;
  int col0 = blockIdx.y * 64;
  if (col0 >= N) return;
  int k0 = blockIdx.x * 64;
  const float* W = (z == 0) ? qw : (z == 1) ? kvw : pw;
  __shared__ float T[64][65];
  int t = threadIdx.x;
  int kl = t >> 4, c4 = (t & 15) * 4;
#pragma unroll
  for (int i = 0; i < 4; i++) {
    float4 v = *(const float4*)&W[(size_t)(k0 + kl + i * 16) * N + col0 + c4];
    T[kl + i * 16][c4 + 0] = v.x; T[kl + i * 16][c4 + 1] = v.y;
    T[kl + i * 16][c4 + 2] = v.z; T[kl + i * 16][c4 + 3] = v.w;
  }
  __syncthreads();
#pragma unroll
  for (int p = 0; p < 2; p++) {
    int cl = (t >> 3) + p * 32, k8 = (t & 7) * 8;
    u16 hi[8], lo[8];
#pragma unroll
    for (int j = 0; j < 8; j++) {
      float f = T[k8 + j][cl];
      u16 hv = f2bf(f);
      hi[j] = hv;
      lo[j] = f2bf(f - bf2f(hv));
    }
    size_t o = (size_t)(col0 + cl) * 512 + k0 + k8;
    if (z == 0) *(uint4*)&Wtq[o] = *(const uint4*)hi;
    else if (z == 1) *(uint4*)&Wtkv[o] = *(const uint4*)hi;
    else { *(uint4*)&Wph[o] = *(const uint4*)hi; *(uint4*)&Wpl[o] = *(const uint4*)lo; }
  }
}

// ---------------- MFMA GEMM: qkv (A[8192][512]bf16 x Wt[N][512]) ------------
// tile 128 rows x 64 cols, BK=64, swizzled LDS (16B-unit XOR), m97 2-phase
__global__ __launch_bounds__(256) void gemm_qkv(
    const u16* __restrict__ A, const u16* __restrict__ Wt,
    const float* __restrict__ bias, int outOffset,
    u16* __restrict__ Qb, u16* __restrict__ Kb, u16* __restrict__ Vt) {
  __shared__ __attribute__((aligned(16))) u16 As[128 * 64];
  __shared__ __attribute__((aligned(16))) u16 Bs[64 * 64];
  int t = threadIdx.x, wid = t >> 6, lane = t & 63, lr = lane & 15, lg = lane >> 4;
  int row0 = blockIdx.y * 128, colb0 = blockIdx.x * 64;
  int wr = wid >> 1, wc = wid & 1;  // wave: 64 rows x 32 cols
  f32x4 acc[4][2];
#pragma unroll
  for (int m = 0; m < 4; m++)
#pragma unroll
    for (int n = 0; n < 2; n++) acc[m][n] = (f32x4){0.f, 0.f, 0.f, 0.f};

  for (int k0 = 0; k0 < 512; k0 += 64) {
    __syncthreads();
#pragma unroll
    for (int it = 0; it < 4; it++) {          // A: 16KB, 4 chunks/wave
      int idx = (wid * 4 + it) * 64 + lane;
      int r = idx >> 3, sg = idx & 7;
      gl_lds16(A + (size_t)(row0 + r) * 512 + k0 + ((sg ^ (r & 7)) * 8),
               (char*)As + (wid * 4 + it) * 1024);
    }
#pragma unroll
    for (int it = 0; it < 2; it++) {          // B: 8KB, 2 chunks/wave
      int idx = (wid * 2 + it) * 64 + lane;
      int r = idx >> 3, sg = idx & 7;
      gl_lds16(Wt + (size_t)(colb0 + r) * 512 + k0 + ((sg ^ (r & 7)) * 8),
               (char*)Bs + (wid * 2 + it) * 1024);
    }
    __syncthreads();
#pragma unroll
    for (int kk = 0; kk < 2; kk++) {
      bf16x8 bfr[2];
#pragma unroll
      for (int n = 0; n < 2; n++) {
        int col = wc * 32 + n * 16 + lr;
        bfr[n] = *(const bf16x8*)((const char*)Bs + col * 128 + (((kk * 4 + lg) ^ (col & 7)) << 4));
      }
#pragma unroll
      for (int m = 0; m < 4; m++) {
        int row = wr * 64 + m * 16 + lr;
        bf16x8 af = *(const bf16x8*)((const char*)As + row * 128 + (((kk * 4 + lg) ^ (row & 7)) << 4));
#pragma unroll
        for (int n = 0; n < 2; n++)
          acc[m][n] = __builtin_amdgcn_mfma_f32_16x16x32_bf16(af, bfr[n], acc[m][n], 0, 0, 0);
      }
    }
  }
  // epilogue: split into Q / K / Vt per cat-channel map
#pragma unroll
  for (int m = 0; m < 4; m++)
#pragma unroll
    for (int n = 0; n < 2; n++) {
      int colg = colb0 + wc * 32 + n * 16 + lr;
      int ch = outOffset + colg;
      int h = ch / 192, role = (ch >> 6) % 3, d = ch & 63;
      float bs = bias[colg];
      int growb = row0 + wr * 64 + m * 16 + lg * 4;
      int nn = growb >> 10, ssi0 = growb & (S - 1);
      size_t nh = (size_t)(nn * HEADS + h);
      if (role == 2) {
        u16 pk[4];
#pragma unroll
        for (int r = 0; r < 4; r++) pk[r] = f2bf(acc[m][n][r] + bs);
        *(uint2*)&Vt[(nh * DH + d) * S + ssi0] = *(const uint2*)pk;
      } else {
        u16* dst = (role == 0) ? Qb : Kb;
#pragma unroll
        for (int r = 0; r < 4; r++)
          dst[(nh * S + ssi0 + r) * DH + d] = f2bf(acc[m][n][r] + bs);
      }
    }
}

// ---------------- MFMA GEMM: proj (obuf f32 -> out NCHW), W split hi+lo -----
// tile 64 ch x 128 rows; operands swapped so D cols = si (coalesced NCHW write)
__global__ __launch_bounds__(256) void gemm_proj(
    const float* __restrict__ Aof, const u16* __restrict__ Wh, const u16* __restrict__ Wl,
    const float* __restrict__ bias, float* __restrict__ out) {
  __shared__ __attribute__((aligned(16))) u16 As[128 * 64];
  __shared__ __attribute__((aligned(16))) u16 Bh[64 * 64];
  __shared__ __attribute__((aligned(16))) u16 Bl[64 * 64];
  int t = threadIdx.x, wid = t >> 6, lane = t & 63, lr = lane & 15, lg = lane >> 4;
  int ch0 = blockIdx.x * 64, row0 = blockIdx.y * 128;
  int wc = wid & 1, wr = wid >> 1;  // wave: 32 ch x 64 rows
  f32x4 acc[2][4];
#pragma unroll
  for (int m = 0; m < 2; m++)
#pragma unroll
    for (int n = 0; n < 4; n++) acc[m][n] = (f32x4){0.f, 0.f, 0.f, 0.f};

  for (int k0 = 0; k0 < 512; k0 += 64) {
    __syncthreads();
    // stage A from f32 (reg-staged, convert to bf16, swizzled ds_write)
#pragma unroll
    for (int i = 0; i < 8; i++) {
      int e4 = (t + i * 256) * 4;
      int r = e4 >> 6, kl = e4 & 63;
      float4 v = *(const float4*)&Aof[(size_t)(row0 + r) * 512 + k0 + kl];
      u16 pk[4] = {f2bf(v.x), f2bf(v.y), f2bf(v.z), f2bf(v.w)};
      *(uint2*)((char*)As + r * 128 + ((kl * 2) ^ ((r & 7) << 4))) = *(const uint2*)pk;
    }
#pragma unroll
    for (int it = 0; it < 2; it++) {
      int idx = (wid * 2 + it) * 64 + lane;
      int r = idx >> 3, sg = idx & 7;
      size_t go = (size_t)(ch0 + r) * 512 + k0 + ((sg ^ (r & 7)) * 8);
      gl_lds16(Wh + go, (char*)Bh + (wid * 2 + it) * 1024);
      gl_lds16(Wl + go, (char*)Bl + (wid * 2 + it) * 1024);
    }
    __syncthreads();
#pragma unroll
    for (int kk = 0; kk < 2; kk++) {
      bf16x8 ar[4];
#pragma unroll
      for (int n = 0; n < 4; n++) {
        int row = wr * 64 + n * 16 + lr;
        ar[n] = *(const bf16x8*)((const char*)As + row * 128 + (((kk * 4 + lg) ^ (row & 7)) << 4));
      }
#pragma unroll
      for (int m = 0; m < 2; m++) {
        int ch = wc * 32 + m * 16 + lr;
        bf16x8 bh = *(const bf16x8*)((const char*)Bh + ch * 128 + (((kk * 4 + lg) ^ (ch & 7)) << 4));
        bf16x8 bl = *(const bf16x8*)((const char*)Bl + ch * 128 + (((kk * 4 + lg) ^ (ch & 7)) << 4));
#pragma unroll
        for (int n = 0; n < 4; n++) {
          acc[m][n] = __builtin_amdgcn_mfma_f32_16x16x32_bf16(bh, ar[n], acc[m][n], 0, 0, 0);
          acc[m][n] = __builtin_amdgcn_mfma_f32_16x16x32_bf16(bl, ar[n], acc[m][n], 0, 0, 0);
        }
      }
    }
  }
  // epilogue: D row = ch, D col = si -> coalesced NCHW writes
#pragma unroll
  for (int m = 0; m < 2; m++)
#pragma unroll
    for (int n = 0; n < 4; n++) {
      int rowg = row0 + wr * 64 + n * 16 + lr;
      int nn = rowg >> 10, ssi = rowg & (S - 1);
#pragma unroll
      for (int r = 0; r < 4; r++) {
        int ch = ch0 + wc * 32 + m * 16 + lg * 4 + r;
        out[((size_t)nn * C + ch) * S + ssi] = acc[m][n][r] + bias[ch];
      }
    }
}

// ---------------- MFMA flash attention (unchanged from round 2) -------------
constexpr int KVB = 128;

__global__ __launch_bounds__(256, 2) void attn_kernel(
    const u16* __restrict__ Qbf, const u16* __restrict__ Kbf,
    const u16* __restrict__ Vtb, float* __restrict__ obuf) {
  __shared__ u16 Ks[KVB * DH];
  __shared__ u16 Vs[DH * KVB];
  __shared__ u16 Ps[4][16 * KVB];

  int tid = threadIdx.x;
  int wave = tid >> 6, lane = tid & 63;
  int lr = lane & 15, lg = lane >> 4;
  int qt = blockIdx.x;
  int nh = blockIdx.y;
  const u16* Qg = Qbf + (size_t)nh * S * DH;
  const u16* Kg = Kbf + (size_t)nh * S * DH;
  const u16* Vg = Vtb + (size_t)nh * DH * S;

  int qrow = qt * 64 + wave * 16 + lr;
  bf16x8 qf0 = *(const bf16x8*)(Qg + (size_t)qrow * DH + lg * 8);
  bf16x8 qf1 = *(const bf16x8*)(Qg + (size_t)qrow * DH + lg * 8 + 32);

  f32x4 oacc[4];
  float m_r[4], l_r[4];
#pragma unroll
  for (int dt = 0; dt < 4; dt++) oacc[dt] = (f32x4){0.f, 0.f, 0.f, 0.f};
#pragma unroll
  for (int r = 0; r < 4; r++) { m_r[r] = -1e30f; l_r[r] = 0.f; }

  char* Pw = (char*)&Ps[wave][0];

  for (int kb = 0; kb < S / KVB; kb++) {
    __syncthreads();
    {
      const uint4* Ksrc = (const uint4*)(Kg + (size_t)kb * KVB * DH);
#pragma unroll
      for (int it = 0; it < 4; it++) {
        int e = tid + it * 256;
        int row = e >> 3, off = e & 7;
        uint4 val = Ksrc[e];
        int b = row * 128 + ((off * 16) ^ ((row & 7) << 4));
        *(uint4*)((char*)Ks + b) = val;
      }
#pragma unroll
      for (int it = 0; it < 4; it++) {
        int e = tid + it * 256;
        int d = e >> 4, off = e & 15;
        uint4 val = *(const uint4*)((const char*)Vg + (size_t)d * 2048 + kb * 256 + off * 16);
        int b = d * 256 + ((off * 16) ^ ((d & 7) << 4));
        *(uint4*)((char*)Vs + b) = val;
      }
    }
    __syncthreads();

    f32x4 sc[8];
#pragma unroll
    for (int t = 0; t < 8; t++) sc[t] = (f32x4){0.f, 0.f, 0.f, 0.f};
#pragma unroll
    for (int t = 0; t < 8; t++) {
      int key = t * 16 + lr;
      int b0 = key * 128 + ((lg * 16) ^ ((key & 7) << 4));
      int b1 = key * 128 + (((lg * 8 + 32) * 2) ^ ((key & 7) << 4));
      bf16x8 kf0 = *(const bf16x8*)((const char*)Ks + b0);
      bf16x8 kf1 = *(const bf16x8*)((const char*)Ks + b1);
      sc[t] = __builtin_amdgcn_mfma_f32_16x16x32_bf16(qf0, kf0, sc[t], 0, 0, 0);
      sc[t] = __builtin_amdgcn_mfma_f32_16x16x32_bf16(qf1, kf1, sc[t], 0, 0, 0);
    }

    float tmax[4] = {-1e30f, -1e30f, -1e30f, -1e30f};
#pragma unroll
    for (int t = 0; t < 8; t++)
#pragma unroll
      for (int r = 0; r < 4; r++) {
        sc[t][r] *= 0.125f;
        tmax[r] = fmaxf(tmax[r], sc[t][r]);
      }
#pragma unroll
    for (int off = 8; off >= 1; off >>= 1)
#pragma unroll
      for (int r = 0; r < 4; r++) tmax[r] = fmaxf(tmax[r], __shfl_xor(tmax[r], off));

    float corr[4];
#pragma unroll
    for (int r = 0; r < 4; r++) {
      float mn = fmaxf(m_r[r], tmax[r]);
      corr[r] = __expf(m_r[r] - mn);
      m_r[r] = mn;
    }

    float rsum[4] = {0.f, 0.f, 0.f, 0.f};
#pragma unroll
    for (int t = 0; t < 8; t++)
#pragma unroll
      for (int r = 0; r < 4; r++) {
        float p = __expf(sc[t][r] - m_r[r]);
        rsum[r] += p;
        int q = lg * 4 + r, key = t * 16 + lr;
        int b = q * 256 + ((key * 2) ^ ((q & 7) << 4));
        *(u16*)(Pw + b) = f2bf(p);
      }
#pragma unroll
    for (int off = 8; off >= 1; off >>= 1)
#pragma unroll
      for (int r = 0; r < 4; r++) rsum[r] += __shfl_xor(rsum[r], off);
#pragma unroll
    for (int r = 0; r < 4; r++) l_r[r] = l_r[r] * corr[r] + rsum[r];
#pragma unroll
    for (int dt = 0; dt < 4; dt++)
#pragma unroll
      for (int r = 0; r < 4; r++) oacc[dt][r] *= corr[r];

#pragma unroll
    for (int kk = 0; kk < 4; kk++) {
      int key0 = lg * 8 + kk * 32;
      int bp = lr * 256 + ((key0 * 2) ^ ((lr & 7) << 4));
      bf16x8 pf = *(const bf16x8*)((const char*)Pw + bp);
#pragma unroll
      for (int dt = 0; dt < 4; dt++) {
        int dd = dt * 16 + lr;
        int bv = dd * 256 + ((key0 * 2) ^ ((dd & 7) << 4));
        bf16x8 vf = *(const bf16x8*)((const char*)Vs + bv);
        oacc[dt] = __builtin_amdgcn_mfma_f32_16x16x32_bf16(pf, vf, oacc[dt], 0, 0, 0);
      }
    }
  }

  int n = nh >> 3, h = nh & 7;
#pragma unroll
  for (int dt = 0; dt < 4; dt++)
#pragma unroll
    for (int r = 0; r < 4; r++) {
      int q = qt * 64 + wave * 16 + lg * 4 + r;
      int d = dt * 16 + lr;
      obuf[((size_t)n * S + q) * C + h * DH + d] = oacc[dt][r] / l_r[r];
    }
}

}  // namespace

extern "C" void kernel_launch(void* const* d_in, const int* in_sizes, int n_in,
                              void* d_out, int out_size, void* d_ws, size_t ws_size,
                              hipStream_t stream) {
  const float* x       = (const float*)d_in[0];
  const float* qx      = (const float*)d_in[1];
  const float* q_ln_g  = (const float*)d_in[2];
  const float* q_ln_b  = (const float*)d_in[3];
  const float* q_w     = (const float*)d_in[4];
  const float* q_b     = (const float*)d_in[5];
  const float* kv_ln_g = (const float*)d_in[6];
  const float* kv_ln_b = (const float*)d_in[7];
  const float* kv_w    = (const float*)d_in[8];
  const float* kv_b    = (const float*)d_in[9];
  const float* proj_w  = (const float*)d_in[10];
  const float* proj_b  = (const float*)d_in[11];
  float* out = (float*)d_out;

  float* ws = (float*)d_ws;
  float* mu_x = ws;
  float* rs_x = ws + RTOT;
  float* mu_q = ws + 2 * RTOT;
  float* rs_q = ws + 3 * RTOT;
  float* obuf = ws + 4 * RTOT;                       // [8192][512] f32
  u16* u = (u16*)(obuf + (size_t)RTOT * C);
  u16* Xkv  = u;                u += (size_t)RTOT * C;
  u16* Xq   = u;                u += (size_t)RTOT * C;
  u16* Wtq  = u;                u += (size_t)C * C;
  u16* Wtkv = u;                u += (size_t)2 * C * C;
  u16* Wph  = u;                u += (size_t)C * C;
  u16* Wpl  = u;                u += (size_t)C * C;
  u16* Qb   = u;                u += (size_t)NBATCH * HEADS * S * DH;
  u16* Kb   = u;                u += (size_t)NBATCH * HEADS * S * DH;
  u16* Vt   = u;

  hipLaunchKernelGGL(ln_stats_kernel, dim3(RTOT / 64, 2), dim3(256), 0, stream,
                     x, qx, mu_x, rs_x, mu_q, rs_q);
  hipLaunchKernelGGL(ln_apply_tr, dim3(S / 64, C / 64, 2 * NBATCH), dim3(256), 0, stream,
                     x, qx, mu_x, rs_x, mu_q, rs_q,
                     kv_ln_g, kv_ln_b, q_ln_g, q_ln_b, Xkv, Xq);
  hipLaunchKernelGGL(prep_w, dim3(8, 16, 3), dim3(256), 0, stream,
                     q_w, kv_w, proj_w, Wtq, Wtkv, Wph, Wpl);
  hipLaunchKernelGGL(gemm_qkv, dim3(C / 64, RTOT / 128), dim3(256), 0, stream,
                     Xq, Wtq, q_b, 0, Qb, Kb, Vt);
  hipLaunchKernelGGL(gemm_qkv, dim3(2 * C / 64, RTOT / 128), dim3(256), 0, stream,
                     Xkv, Wtkv, kv_b, C, Qb, Kb, Vt);
  hipLaunchKernelGGL(attn_kernel, dim3(S / 64, NBATCH * HEADS), dim3(256), 0, stream,
                     Qb, Kb, Vt, obuf);
  hipLaunchKernelGGL(gemm_proj, dim3(C / 64, RTOT / 128), dim3(256), 0, stream,
                     obuf, Wph, Wpl, proj_b, out);
}

// Round 4
// 110.650 us; speedup vs baseline: 26.0587x; 1.4332x over previous
//
#include <hip/hip_runtime.h>
#include <math.h>

namespace {

constexpr int S = 1024;
constexpr int C = 512;
constexpr int NBATCH = 8;
constexpr int RTOT = NBATCH * S;  // 8192
constexpr int HEADS = 8;
constexpr int DH = 64;

typedef __attribute__((ext_vector_type(8))) short bf16x8;
typedef __attribute__((ext_vector_type(4))) float f32x4;
typedef unsigned short u16;
typedef unsigned int u32;

__device__ __forceinline__ u16 f2bf(float x) {
  union { float f; u32 u; } v; v.f = x;
  u32 r = v.u + 0x7FFF + ((v.u >> 16) & 1);
  return (u16)(r >> 16);
}
__device__ __forceinline__ float bf2f(u16 b) {
  union { u32 u; float f; } v; v.u = (u32)b << 16; return v.f;
}
__device__ __forceinline__ void gl_lds16(const void* g, void* l) {
  auto gp = (const __attribute__((address_space(1))) u32*)g;
  auto lp = (__attribute__((address_space(3))) u32*)l;
  __builtin_amdgcn_global_load_lds(gp, lp, 16, 0, 0);
}

// ---------------- LN stats ---------------------------------------------------
__global__ void ln_stats_kernel(const float* __restrict__ x,
                                const float* __restrict__ qx,
                                float* __restrict__ mu_x, float* __restrict__ rs_x,
                                float* __restrict__ mu_q, float* __restrict__ rs_q) {
  __shared__ float Ssum[4][64], Ssq[4][64];
  int t = threadIdx.x;
  int r0 = blockIdx.x * 64;
  const float* in = blockIdx.y ? qx : x;
  float* mu = blockIdx.y ? mu_q : mu_x;
  float* rs = blockIdx.y ? rs_q : rs_x;
  int n = r0 >> 10, siL = (r0 & (S - 1)) + (t & 63);
  const float* p = in + ((size_t)n * C + (t >> 6) * 128) * S + siL;
  float s = 0.f, sq = 0.f;
#pragma unroll 8
  for (int c = 0; c < 128; c++) { float v = p[(size_t)c * S]; s += v; sq += v * v; }
  Ssum[t >> 6][t & 63] = s; Ssq[t >> 6][t & 63] = sq;
  __syncthreads();
  if (t < 64) {
    float ss = Ssum[0][t] + Ssum[1][t] + Ssum[2][t] + Ssum[3][t];
    float q2 = Ssq[0][t] + Ssq[1][t] + Ssq[2][t] + Ssq[3][t];
    float m = ss * (1.0f / C);
    float var = q2 * (1.0f / C) - m * m;
    mu[r0 + t] = m;
    rs[r0 + t] = rsqrtf(var + 1e-5f);
  }
}

// ---------------- LN apply + NCHW->(row,c) transpose + bf16 -----------------
__global__ void ln_apply_tr(const float* __restrict__ x, const float* __restrict__ qx,
                            const float* __restrict__ mu_x, const float* __restrict__ rs_x,
                            const float* __restrict__ mu_q, const float* __restrict__ rs_q,
                            const float* __restrict__ gx, const float* __restrict__ bx,
                            const float* __restrict__ gq, const float* __restrict__ bq,
                            u16* __restrict__ Xkv, u16* __restrict__ Xq) {
  __shared__ float T[64][65];
  int t = threadIdx.x;
  int si0 = blockIdx.x * 64, c0 = blockIdx.y * 64;
  int isq = blockIdx.z & 1, n = blockIdx.z >> 1;
  const float* in = isq ? qx : x;
  const float* mu = isq ? mu_q : mu_x;
  const float* rs = isq ? rs_q : rs_x;
  const float* g = isq ? gq : gx;
  const float* be = isq ? bq : bx;
  u16* out = isq ? Xq : Xkv;

  int sl4 = (t & 15) * 4, cl = t >> 4;
  float4 mu4 = *(const float4*)&mu[n * S + si0 + sl4];
  float4 rs4 = *(const float4*)&rs[n * S + si0 + sl4];
#pragma unroll
  for (int i = 0; i < 4; i++) {
    int c = c0 + cl + i * 16;
    float4 v = *(const float4*)&in[((size_t)n * C + c) * S + si0 + sl4];
    float gg = g[c], bb = be[c];
    T[sl4 + 0][cl + i * 16] = (v.x - mu4.x) * rs4.x * gg + bb;
    T[sl4 + 1][cl + i * 16] = (v.y - mu4.y) * rs4.y * gg + bb;
    T[sl4 + 2][cl + i * 16] = (v.z - mu4.z) * rs4.z * gg + bb;
    T[sl4 + 3][cl + i * 16] = (v.w - mu4.w) * rs4.w * gg + bb;
  }
  __syncthreads();
#pragma unroll
  for (int p = 0; p < 2; p++) {
    int sl = (t >> 3) + p * 32, c8 = (t & 7) * 8;
    u16 pk[8];
#pragma unroll
    for (int j = 0; j < 8; j++) pk[j] = f2bf(T[sl][c8 + j]);
    *(uint4*)&out[((size_t)(n * S + si0 + sl)) * C + c0 + c8] = *(const uint4*)pk;
  }
}

// ---------------- Weight prep: W[k][col] -> Wt[col][k] bf16 (+split for proj)
__global__ void prep_w(const float* __restrict__ qw, const float* __restrict__ kvw,
                       const float* __restrict__ pw,
                       u16* __restrict__ Wtq, u16* __restrict__ Wtkv,
                       u16* __restrict__ Wph, u16* __restrict__ Wpl) {
  int z = blockIdx.z;
  int N = (z == 1) ? 1024 : 512;
  int col0 = blockIdx.y * 64;
  if (col0 >= N) return;
  int k0 = blockIdx.x * 64;
  const float* W = (z == 0) ? qw : (z == 1) ? kvw : pw;
  __shared__ float T[64][65];
  int t = threadIdx.x;
  int kl = t >> 4, c4 = (t & 15) * 4;
#pragma unroll
  for (int i = 0; i < 4; i++) {
    float4 v = *(const float4*)&W[(size_t)(k0 + kl + i * 16) * N + col0 + c4];
    T[kl + i * 16][c4 + 0] = v.x; T[kl + i * 16][c4 + 1] = v.y;
    T[kl + i * 16][c4 + 2] = v.z; T[kl + i * 16][c4 + 3] = v.w;
  }
  __syncthreads();
#pragma unroll
  for (int p = 0; p < 2; p++) {
    int cl = (t >> 3) + p * 32, k8 = (t & 7) * 8;
    u16 hi[8], lo[8];
#pragma unroll
    for (int j = 0; j < 8; j++) {
      float f = T[k8 + j][cl];
      u16 hv = f2bf(f);
      hi[j] = hv;
      lo[j] = f2bf(f - bf2f(hv));
    }
    size_t o = (size_t)(col0 + cl) * 512 + k0 + k8;
    if (z == 0) *(uint4*)&Wtq[o] = *(const uint4*)hi;
    else if (z == 1) *(uint4*)&Wtkv[o] = *(const uint4*)hi;
    else { *(uint4*)&Wph[o] = *(const uint4*)hi; *(uint4*)&Wpl[o] = *(const uint4*)lo; }
  }
}

// ---------------- MFMA GEMM: qkv --------------------------------------------
__global__ __launch_bounds__(256) void gemm_qkv(
    const u16* __restrict__ A, const u16* __restrict__ Wt,
    const float* __restrict__ bias, int outOffset,
    u16* __restrict__ Qb, u16* __restrict__ Kb, u16* __restrict__ Vt) {
  __shared__ __attribute__((aligned(16))) u16 As[128 * 64];
  __shared__ __attribute__((aligned(16))) u16 Bs[64 * 64];
  int t = threadIdx.x, wid = t >> 6, lane = t & 63, lr = lane & 15, lg = lane >> 4;
  int row0 = blockIdx.y * 128, colb0 = blockIdx.x * 64;
  int wr = wid >> 1, wc = wid & 1;
  f32x4 acc[4][2];
#pragma unroll
  for (int m = 0; m < 4; m++)
#pragma unroll
    for (int n = 0; n < 2; n++) acc[m][n] = (f32x4){0.f, 0.f, 0.f, 0.f};

  for (int k0 = 0; k0 < 512; k0 += 64) {
    __syncthreads();
#pragma unroll
    for (int it = 0; it < 4; it++) {
      int idx = (wid * 4 + it) * 64 + lane;
      int r = idx >> 3, sg = idx & 7;
      gl_lds16(A + (size_t)(row0 + r) * 512 + k0 + ((sg ^ (r & 7)) * 8),
               (char*)As + (wid * 4 + it) * 1024);
    }
#pragma unroll
    for (int it = 0; it < 2; it++) {
      int idx = (wid * 2 + it) * 64 + lane;
      int r = idx >> 3, sg = idx & 7;
      gl_lds16(Wt + (size_t)(colb0 + r) * 512 + k0 + ((sg ^ (r & 7)) * 8),
               (char*)Bs + (wid * 2 + it) * 1024);
    }
    __syncthreads();
#pragma unroll
    for (int kk = 0; kk < 2; kk++) {
      bf16x8 bfr[2];
#pragma unroll
      for (int n = 0; n < 2; n++) {
        int col = wc * 32 + n * 16 + lr;
        bfr[n] = *(const bf16x8*)((const char*)Bs + col * 128 + (((kk * 4 + lg) ^ (col & 7)) << 4));
      }
#pragma unroll
      for (int m = 0; m < 4; m++) {
        int row = wr * 64 + m * 16 + lr;
        bf16x8 af = *(const bf16x8*)((const char*)As + row * 128 + (((kk * 4 + lg) ^ (row & 7)) << 4));
#pragma unroll
        for (int n = 0; n < 2; n++)
          acc[m][n] = __builtin_amdgcn_mfma_f32_16x16x32_bf16(af, bfr[n], acc[m][n], 0, 0, 0);
      }
    }
  }
#pragma unroll
  for (int m = 0; m < 4; m++)
#pragma unroll
    for (int n = 0; n < 2; n++) {
      int colg = colb0 + wc * 32 + n * 16 + lr;
      int ch = outOffset + colg;
      int h = ch / 192, role = (ch >> 6) % 3, d = ch & 63;
      float bs = bias[colg];
      float qsc = (role == 0) ? 0.125f : 1.0f;   // fold 1/sqrt(DH) into Q
      int growb = row0 + wr * 64 + m * 16 + lg * 4;
      int nn = growb >> 10, ssi0 = growb & (S - 1);
      size_t nh = (size_t)(nn * HEADS + h);
      if (role == 2) {
        u16 pk[4];
#pragma unroll
        for (int r = 0; r < 4; r++) pk[r] = f2bf(acc[m][n][r] + bs);
        *(uint2*)&Vt[(nh * DH + d) * S + ssi0] = *(const uint2*)pk;
      } else {
        u16* dst = (role == 0) ? Qb : Kb;
#pragma unroll
        for (int r = 0; r < 4; r++)
          dst[(nh * S + ssi0 + r) * DH + d] = f2bf((acc[m][n][r] + bs) * qsc);
      }
    }
}

// ---------------- MFMA GEMM: proj (Obf bf16 -> out NCHW), W split hi+lo -----
__global__ __launch_bounds__(256) void gemm_proj(
    const u16* __restrict__ Aob, const u16* __restrict__ Wh, const u16* __restrict__ Wl,
    const float* __restrict__ bias, float* __restrict__ out) {
  __shared__ __attribute__((aligned(16))) u16 As[128 * 64];
  __shared__ __attribute__((aligned(16))) u16 Bh[64 * 64];
  __shared__ __attribute__((aligned(16))) u16 Bl[64 * 64];
  int t = threadIdx.x, wid = t >> 6, lane = t & 63, lr = lane & 15, lg = lane >> 4;
  int ch0 = blockIdx.x * 64, row0 = blockIdx.y * 128;
  int wc = wid & 1, wr = wid >> 1;
  f32x4 acc[2][4];
#pragma unroll
  for (int m = 0; m < 2; m++)
#pragma unroll
    for (int n = 0; n < 4; n++) acc[m][n] = (f32x4){0.f, 0.f, 0.f, 0.f};

  for (int k0 = 0; k0 < 512; k0 += 64) {
    __syncthreads();
#pragma unroll
    for (int it = 0; it < 4; it++) {
      int idx = (wid * 4 + it) * 64 + lane;
      int r = idx >> 3, sg = idx & 7;
      gl_lds16(Aob + (size_t)(row0 + r) * 512 + k0 + ((sg ^ (r & 7)) * 8),
               (char*)As + (wid * 4 + it) * 1024);
    }
#pragma unroll
    for (int it = 0; it < 2; it++) {
      int idx = (wid * 2 + it) * 64 + lane;
      int r = idx >> 3, sg = idx & 7;
      size_t go = (size_t)(ch0 + r) * 512 + k0 + ((sg ^ (r & 7)) * 8);
      gl_lds16(Wh + go, (char*)Bh + (wid * 2 + it) * 1024);
      gl_lds16(Wl + go, (char*)Bl + (wid * 2 + it) * 1024);
    }
    __syncthreads();
#pragma unroll
    for (int kk = 0; kk < 2; kk++) {
      bf16x8 ar[4];
#pragma unroll
      for (int n = 0; n < 4; n++) {
        int row = wr * 64 + n * 16 + lr;
        ar[n] = *(const bf16x8*)((const char*)As + row * 128 + (((kk * 4 + lg) ^ (row & 7)) << 4));
      }
#pragma unroll
      for (int m = 0; m < 2; m++) {
        int ch = wc * 32 + m * 16 + lr;
        bf16x8 bh = *(const bf16x8*)((const char*)Bh + ch * 128 + (((kk * 4 + lg) ^ (ch & 7)) << 4));
        bf16x8 bl = *(const bf16x8*)((const char*)Bl + ch * 128 + (((kk * 4 + lg) ^ (ch & 7)) << 4));
#pragma unroll
        for (int n = 0; n < 4; n++) {
          acc[m][n] = __builtin_amdgcn_mfma_f32_16x16x32_bf16(bh, ar[n], acc[m][n], 0, 0, 0);
          acc[m][n] = __builtin_amdgcn_mfma_f32_16x16x32_bf16(bl, ar[n], acc[m][n], 0, 0, 0);
        }
      }
    }
  }
#pragma unroll
  for (int m = 0; m < 2; m++)
#pragma unroll
    for (int n = 0; n < 4; n++) {
      int rowg = row0 + wr * 64 + n * 16 + lr;
      int nn = rowg >> 10, ssi = rowg & (S - 1);
#pragma unroll
      for (int r = 0; r < 4; r++) {
        int ch = ch0 + wc * 32 + m * 16 + lg * 4 + r;
        out[((size_t)nn * C + ch) * S + ssi] = acc[m][n][r] + bias[ch];
      }
    }
}

// ---------------- MFMA flash attention, swapped-QK^T, KVB=64, double-buffered
// Q pre-scaled by 0.125 upstream. Per block: 4 waves x 16 q-rows.
// sc[t][r]: key = t*16 + lg*4 + r, q = lr  (D: col=q, row=key-in-tile)
constexpr int KVB = 64;

__global__ __launch_bounds__(256) void attn_kernel(
    const u16* __restrict__ Qbf, const u16* __restrict__ Kbf,
    const u16* __restrict__ Vtb, u16* __restrict__ Obf) {
  __shared__ __attribute__((aligned(16))) u16 Ks[2][KVB * DH];   // 8KB each
  __shared__ __attribute__((aligned(16))) u16 Vs[2][DH * KVB];   // 8KB each
  __shared__ __attribute__((aligned(16))) u16 Ps[4][16 * KVB];   // 2KB/wave

  int tid = threadIdx.x;
  int wave = tid >> 6, lane = tid & 63;
  int lr = lane & 15, lg = lane >> 4;
  // XCD-chunked swizzle: 1024 blocks, 8 XCDs, 128/chunk -> same nh co-XCD
  int w = (blockIdx.x & 7) * 128 + (blockIdx.x >> 3);
  int qt = w & 15, nh = w >> 4;
  const u16* Qg = Qbf + (size_t)nh * S * DH;
  const u16* Kg = Kbf + (size_t)nh * S * DH;
  const u16* Vg = Vtb + (size_t)nh * DH * S;

  int qrow = qt * 64 + wave * 16 + lr;
  bf16x8 qf0 = *(const bf16x8*)(Qg + (size_t)qrow * DH + lg * 8);
  bf16x8 qf1 = *(const bf16x8*)(Qg + (size_t)qrow * DH + lg * 8 + 32);

  f32x4 oacc[4];
#pragma unroll
  for (int dt = 0; dt < 4; dt++) oacc[dt] = (f32x4){0.f, 0.f, 0.f, 0.f};
  float m_run = -1e30f, l_run = 0.f;   // stats for q = lr (scalar per lane)

  char* Pw = (char*)&Ps[wave][0];
  int e0i = tid, e1i = tid + 256;       // staging element ids
  int r0 = e0i >> 3, sg0 = e0i & 7, r1 = e1i >> 3, sg1 = e1i & 7;
  char* kd0 = (char*)&Ks[0][0] + (e0i & ~63) * 16;
  char* kd1 = (char*)&Ks[0][0] + (e1i & ~63) * 16;
  char* vd0 = (char*)&Vs[0][0] + (e0i & ~63) * 16;
  char* vd1 = (char*)&Vs[0][0] + (e1i & ~63) * 16;

#define STAGE(kb, b)                                                             \
  do {                                                                           \
    gl_lds16(Kg + (size_t)((kb) * KVB + r0) * 64 + ((sg0 ^ (r0 & 7)) * 8),       \
             kd0 + (b) * (KVB * DH * 2));                                        \
    gl_lds16(Kg + (size_t)((kb) * KVB + r1) * 64 + ((sg1 ^ (r1 & 7)) * 8),       \
             kd1 + (b) * (KVB * DH * 2));                                        \
    gl_lds16(Vg + (size_t)r0 * S + (kb) * KVB + ((sg0 ^ (r0 & 7)) * 8),          \
             vd0 + (b) * (KVB * DH * 2));                                        \
    gl_lds16(Vg + (size_t)r1 * S + (kb) * KVB + ((sg1 ^ (r1 & 7)) * 8),          \
             vd1 + (b) * (KVB * DH * 2));                                        \
  } while (0)

  STAGE(0, 0);

  for (int kb = 0; kb < S / KVB; kb++) {
    int cur = kb & 1;
    __syncthreads();                       // buf[cur] ready; buf[cur^1] free
    if (kb + 1 < S / KVB) STAGE(kb + 1, cur ^ 1);

    const char* Kc = (const char*)&Ks[cur][0];
    const char* Vc = (const char*)&Vs[cur][0];

    // QK^T (swapped): sc[t] covers keys t*16..t*16+15
    f32x4 sc[4];
#pragma unroll
    for (int t = 0; t < 4; t++) {
      int key = t * 16 + lr;
      const char* kr = Kc + key * 128;
      bf16x8 kf0 = *(const bf16x8*)(kr + ((lg * 16) ^ ((lr & 7) << 4)));
      bf16x8 kf1 = *(const bf16x8*)(kr + (((lg * 16) + 64) ^ ((lr & 7) << 4)));
      f32x4 z = (f32x4){0.f, 0.f, 0.f, 0.f};
      z = __builtin_amdgcn_mfma_f32_16x16x32_bf16(kf0, qf0, z, 0, 0, 0);
      sc[t] = __builtin_amdgcn_mfma_f32_16x16x32_bf16(kf1, qf1, z, 0, 0, 0);
    }

    // row max (q = lr), reduce over lg via 2 shfls
    float pmax = -1e30f;
#pragma unroll
    for (int t = 0; t < 4; t++) {
      float a = fmaxf(fmaxf(sc[t][0], sc[t][1]), fmaxf(sc[t][2], sc[t][3]));
      pmax = fmaxf(pmax, a);
    }
    pmax = fmaxf(pmax, __shfl_xor(pmax, 16));
    pmax = fmaxf(pmax, __shfl_xor(pmax, 32));

    // defer-max (T13): only rescale when max grew by > 8
    if (!__all(pmax <= m_run + 8.0f)) {
      float mnew = fmaxf(m_run, pmax);
      float corr = __expf(m_run - mnew);
      m_run = mnew;
      l_run *= corr;
      float cr[4];
#pragma unroll
      for (int r = 0; r < 4; r++) cr[r] = __shfl(corr, lg * 4 + r);
#pragma unroll
      for (int dt = 0; dt < 4; dt++)
#pragma unroll
        for (int r = 0; r < 4; r++) oacc[dt][r] *= cr[r];
    }

    // exp, pack to bf16, write P (b64), accumulate row sum
    float psum = 0.f;
#pragma unroll
    for (int t = 0; t < 4; t++) {
      float e0 = __expf(sc[t][0] - m_run);
      float e1 = __expf(sc[t][1] - m_run);
      float e2 = __expf(sc[t][2] - m_run);
      float e3 = __expf(sc[t][3] - m_run);
      psum += (e0 + e1) + (e2 + e3);
      u32 w0 = (u32)f2bf(e0) | ((u32)f2bf(e1) << 16);
      u32 w1 = (u32)f2bf(e2) | ((u32)f2bf(e3) << 16);
      uint2 pw; pw.x = w0; pw.y = w1;
      *(uint2*)(Pw + lr * 128 + ((t * 32 + lg * 8) ^ ((lr & 7) << 4))) = pw;
    }
    psum += __shfl_xor(psum, 16);
    psum += __shfl_xor(psum, 32);
    l_run += psum;

    // PV: O += P(16x64) x V(64x64)
#pragma unroll
    for (int kk = 0; kk < 2; kk++) {
      bf16x8 pf = *(const bf16x8*)(Pw + lr * 128 + ((kk * 64 + lg * 16) ^ ((lr & 7) << 4)));
#pragma unroll
      for (int dt = 0; dt < 4; dt++) {
        int dd = dt * 16 + lr;
        bf16x8 vf = *(const bf16x8*)(Vc + dd * 128 + ((kk * 64 + lg * 16) ^ ((lr & 7) << 4)));
        oacc[dt] = __builtin_amdgcn_mfma_f32_16x16x32_bf16(pf, vf, oacc[dt], 0, 0, 0);
      }
    }
  }
#undef STAGE

  // epilogue -> bf16 O[n][s][c]
  int n = nh >> 3, h = nh & 7;
  float lf[4];
#pragma unroll
  for (int r = 0; r < 4; r++) lf[r] = 1.0f / __shfl(l_run, lg * 4 + r);
#pragma unroll
  for (int dt = 0; dt < 4; dt++)
#pragma unroll
    for (int r = 0; r < 4; r++) {
      int q = qt * 64 + wave * 16 + lg * 4 + r;
      int d = dt * 16 + lr;
      Obf[((size_t)n * S + q) * C + h * DH + d] = f2bf(oacc[dt][r] * lf[r]);
    }
}

}  // namespace

extern "C" void kernel_launch(void* const* d_in, const int* in_sizes, int n_in,
                              void* d_out, int out_size, void* d_ws, size_t ws_size,
                              hipStream_t stream) {
  const float* x       = (const float*)d_in[0];
  const float* qx      = (const float*)d_in[1];
  const float* q_ln_g  = (const float*)d_in[2];
  const float* q_ln_b  = (const float*)d_in[3];
  const float* q_w     = (const float*)d_in[4];
  const float* q_b     = (const float*)d_in[5];
  const float* kv_ln_g = (const float*)d_in[6];
  const float* kv_ln_b = (const float*)d_in[7];
  const float* kv_w    = (const float*)d_in[8];
  const float* kv_b    = (const float*)d_in[9];
  const float* proj_w  = (const float*)d_in[10];
  const float* proj_b  = (const float*)d_in[11];
  float* out = (float*)d_out;

  float* ws = (float*)d_ws;
  float* mu_x = ws;
  float* rs_x = ws + RTOT;
  float* mu_q = ws + 2 * RTOT;
  float* rs_q = ws + 3 * RTOT;
  u16* u = (u16*)(ws + 4 * RTOT);
  u16* Xkv  = u;                u += (size_t)RTOT * C;
  u16* Xq   = u;                u += (size_t)RTOT * C;
  u16* Wtq  = u;                u += (size_t)C * C;
  u16* Wtkv = u;                u += (size_t)2 * C * C;
  u16* Wph  = u;                u += (size_t)C * C;
  u16* Wpl  = u;                u += (size_t)C * C;
  u16* Qb   = u;                u += (size_t)NBATCH * HEADS * S * DH;
  u16* Kb   = u;                u += (size_t)NBATCH * HEADS * S * DH;
  u16* Vt   = u;                u += (size_t)NBATCH * HEADS * S * DH;
  u16* Obf  = u;

  hipLaunchKernelGGL(ln_stats_kernel, dim3(RTOT / 64, 2), dim3(256), 0, stream,
                     x, qx, mu_x, rs_x, mu_q, rs_q);
  hipLaunchKernelGGL(ln_apply_tr, dim3(S / 64, C / 64, 2 * NBATCH), dim3(256), 0, stream,
                     x, qx, mu_x, rs_x, mu_q, rs_q,
                     kv_ln_g, kv_ln_b, q_ln_g, q_ln_b, Xkv, Xq);
  hipLaunchKernelGGL(prep_w, dim3(8, 16, 3), dim3(256), 0, stream,
                     q_w, kv_w, proj_w, Wtq, Wtkv, Wph, Wpl);
  hipLaunchKernelGGL(gemm_qkv, dim3(C / 64, RTOT / 128), dim3(256), 0, stream,
                     Xq, Wtq, q_b, 0, Qb, Kb, Vt);
  hipLaunchKernelGGL(gemm_qkv, dim3(2 * C / 64, RTOT / 128), dim3(256), 0, stream,
                     Xkv, Wtkv, kv_b, C, Qb, Kb, Vt);
  hipLaunchKernelGGL(attn_kernel, dim3(1024), dim3(256), 0, stream,
                     Qb, Kb, Vt, Obf);
  hipLaunchKernelGGL(gemm_proj, dim3(C / 64, RTOT / 128), dim3(256), 0, stream,
                     Obf, Wph, Wpl, proj_b, out);
}

// Round 5
// 106.194 us; speedup vs baseline: 27.1523x; 1.0420x over previous
//
#include <hip/hip_runtime.h>
#include <math.h>

namespace {

constexpr int S = 1024;
constexpr int C = 512;
constexpr int NBATCH = 8;
constexpr int RTOT = NBATCH * S;  // 8192
constexpr int HEADS = 8;
constexpr int DH = 64;

typedef __attribute__((ext_vector_type(8))) short bf16x8;
typedef __attribute__((ext_vector_type(4))) float f32x4;
typedef unsigned short u16;
typedef unsigned int u32;

__device__ __forceinline__ u16 f2bf(float x) {
  union { float f; u32 u; } v; v.f = x;
  u32 r = v.u + 0x7FFF + ((v.u >> 16) & 1);
  return (u16)(r >> 16);
}
__device__ __forceinline__ float bf2f(u16 b) {
  union { u32 u; float f; } v; v.u = (u32)b << 16; return v.f;
}
__device__ __forceinline__ u32 cvtpk(float a, float b) {  // lo=a, hi=b
  u32 r;
  asm("v_cvt_pk_bf16_f32 %0, %1, %2" : "=v"(r) : "v"(a), "v"(b));
  return r;
}
__device__ __forceinline__ void gl_lds16(const void* g, void* l) {
  auto gp = (const __attribute__((address_space(1))) u32*)g;
  auto lp = (__attribute__((address_space(3))) u32*)l;
  __builtin_amdgcn_global_load_lds(gp, lp, 16, 0, 0);
}

// ---------------- LN stats ---------------------------------------------------
__global__ void ln_stats_kernel(const float* __restrict__ x,
                                const float* __restrict__ qx,
                                float* __restrict__ mu_x, float* __restrict__ rs_x,
                                float* __restrict__ mu_q, float* __restrict__ rs_q) {
  __shared__ float Ssum[4][64], Ssq[4][64];
  int t = threadIdx.x;
  int r0 = blockIdx.x * 64;
  const float* in = blockIdx.y ? qx : x;
  float* mu = blockIdx.y ? mu_q : mu_x;
  float* rs = blockIdx.y ? rs_q : rs_x;
  int n = r0 >> 10, siL = (r0 & (S - 1)) + (t & 63);
  const float* p = in + ((size_t)n * C + (t >> 6) * 128) * S + siL;
  float s = 0.f, sq = 0.f;
#pragma unroll 8
  for (int c = 0; c < 128; c++) { float v = p[(size_t)c * S]; s += v; sq += v * v; }
  Ssum[t >> 6][t & 63] = s; Ssq[t >> 6][t & 63] = sq;
  __syncthreads();
  if (t < 64) {
    float ss = Ssum[0][t] + Ssum[1][t] + Ssum[2][t] + Ssum[3][t];
    float q2 = Ssq[0][t] + Ssq[1][t] + Ssq[2][t] + Ssq[3][t];
    float m = ss * (1.0f / C);
    float var = q2 * (1.0f / C) - m * m;
    mu[r0 + t] = m;
    rs[r0 + t] = rsqrtf(var + 1e-5f);
  }
}

// ---------------- LN apply + NCHW->(row,c) transpose + bf16 -----------------
__global__ void ln_apply_tr(const float* __restrict__ x, const float* __restrict__ qx,
                            const float* __restrict__ mu_x, const float* __restrict__ rs_x,
                            const float* __restrict__ mu_q, const float* __restrict__ rs_q,
                            const float* __restrict__ gx, const float* __restrict__ bx,
                            const float* __restrict__ gq, const float* __restrict__ bq,
                            u16* __restrict__ Xkv, u16* __restrict__ Xq) {
  __shared__ float T[64][65];
  int t = threadIdx.x;
  int si0 = blockIdx.x * 64, c0 = blockIdx.y * 64;
  int isq = blockIdx.z & 1, n = blockIdx.z >> 1;
  const float* in = isq ? qx : x;
  const float* mu = isq ? mu_q : mu_x;
  const float* rs = isq ? rs_q : rs_x;
  const float* g = isq ? gq : gx;
  const float* be = isq ? bq : bx;
  u16* out = isq ? Xq : Xkv;

  int sl4 = (t & 15) * 4, cl = t >> 4;
  float4 mu4 = *(const float4*)&mu[n * S + si0 + sl4];
  float4 rs4 = *(const float4*)&rs[n * S + si0 + sl4];
#pragma unroll
  for (int i = 0; i < 4; i++) {
    int c = c0 + cl + i * 16;
    float4 v = *(const float4*)&in[((size_t)n * C + c) * S + si0 + sl4];
    float gg = g[c], bb = be[c];
    T[sl4 + 0][cl + i * 16] = (v.x - mu4.x) * rs4.x * gg + bb;
    T[sl4 + 1][cl + i * 16] = (v.y - mu4.y) * rs4.y * gg + bb;
    T[sl4 + 2][cl + i * 16] = (v.z - mu4.z) * rs4.z * gg + bb;
    T[sl4 + 3][cl + i * 16] = (v.w - mu4.w) * rs4.w * gg + bb;
  }
  __syncthreads();
#pragma unroll
  for (int p = 0; p < 2; p++) {
    int sl = (t >> 3) + p * 32, c8 = (t & 7) * 8;
    u16 pk[8];
#pragma unroll
    for (int j = 0; j < 8; j++) pk[j] = f2bf(T[sl][c8 + j]);
    *(uint4*)&out[((size_t)(n * S + si0 + sl)) * C + c0 + c8] = *(const uint4*)pk;
  }
}

// ---------------- Weight prep: W[k][col] -> Wt[col][k] bf16 (+split for proj)
__global__ void prep_w(const float* __restrict__ qw, const float* __restrict__ kvw,
                       const float* __restrict__ pw,
                       u16* __restrict__ Wtq, u16* __restrict__ Wtkv,
                       u16* __restrict__ Wph, u16* __restrict__ Wpl) {
  int z = blockIdx.z;
  int N = (z == 1) ? 1024 : 512;
  int col0 = blockIdx.y * 64;
  if (col0 >= N) return;
  int k0 = blockIdx.x * 64;
  const float* W = (z == 0) ? qw : (z == 1) ? kvw : pw;
  __shared__ float T[64][65];
  int t = threadIdx.x;
  int kl = t >> 4, c4 = (t & 15) * 4;
#pragma unroll
  for (int i = 0; i < 4; i++) {
    float4 v = *(const float4*)&W[(size_t)(k0 + kl + i * 16) * N + col0 + c4];
    T[kl + i * 16][c4 + 0] = v.x; T[kl + i * 16][c4 + 1] = v.y;
    T[kl + i * 16][c4 + 2] = v.z; T[kl + i * 16][c4 + 3] = v.w;
  }
  __syncthreads();
#pragma unroll
  for (int p = 0; p < 2; p++) {
    int cl = (t >> 3) + p * 32, k8 = (t & 7) * 8;
    u16 hi[8], lo[8];
#pragma unroll
    for (int j = 0; j < 8; j++) {
      float f = T[k8 + j][cl];
      u16 hv = f2bf(f);
      hi[j] = hv;
      lo[j] = f2bf(f - bf2f(hv));
    }
    size_t o = (size_t)(col0 + cl) * 512 + k0 + k8;
    if (z == 0) *(uint4*)&Wtq[o] = *(const uint4*)hi;
    else if (z == 1) *(uint4*)&Wtkv[o] = *(const uint4*)hi;
    else { *(uint4*)&Wph[o] = *(const uint4*)hi; *(uint4*)&Wpl[o] = *(const uint4*)lo; }
  }
}

// ---------------- MFMA GEMM: merged q+kv projection --------------------------
// grid (24, 64): colb<8 -> q GEMM cols, colb>=8 -> kv GEMM cols
__global__ __launch_bounds__(256) void gemm_qkv(
    const u16* __restrict__ Xq, const u16* __restrict__ Xkv,
    const u16* __restrict__ Wtq, const u16* __restrict__ Wtkv,
    const float* __restrict__ q_b, const float* __restrict__ kv_b,
    u16* __restrict__ Qb, u16* __restrict__ Kb, u16* __restrict__ Vt) {
  __shared__ __attribute__((aligned(16))) u16 As[128 * 64];
  __shared__ __attribute__((aligned(16))) u16 Bs[64 * 64];
  int t = threadIdx.x, wid = t >> 6, lane = t & 63, lr = lane & 15, lg = lane >> 4;
  int colb = blockIdx.x;
  const u16* A; const u16* Wt; const float* bias; int ch0;
  if (colb < 8) { A = Xq;  Wt = Wtq  + (size_t)colb * 64 * 512;      bias = q_b  + colb * 64;      ch0 = colb * 64; }
  else          { A = Xkv; Wt = Wtkv + (size_t)(colb - 8) * 64 * 512; bias = kv_b + (colb - 8) * 64; ch0 = 512 + (colb - 8) * 64; }
  int row0 = blockIdx.y * 128;
  int wr = wid >> 1, wc = wid & 1;
  f32x4 acc[4][2];
#pragma unroll
  for (int m = 0; m < 4; m++)
#pragma unroll
    for (int n = 0; n < 2; n++) acc[m][n] = (f32x4){0.f, 0.f, 0.f, 0.f};

  for (int k0 = 0; k0 < 512; k0 += 64) {
    __syncthreads();
#pragma unroll
    for (int it = 0; it < 4; it++) {
      int idx = (wid * 4 + it) * 64 + lane;
      int r = idx >> 3, sg = idx & 7;
      gl_lds16(A + (size_t)(row0 + r) * 512 + k0 + ((sg ^ (r & 7)) * 8),
               (char*)As + (wid * 4 + it) * 1024);
    }
#pragma unroll
    for (int it = 0; it < 2; it++) {
      int idx = (wid * 2 + it) * 64 + lane;
      int r = idx >> 3, sg = idx & 7;
      gl_lds16(Wt + (size_t)r * 512 + k0 + ((sg ^ (r & 7)) * 8),
               (char*)Bs + (wid * 2 + it) * 1024);
    }
    __syncthreads();
#pragma unroll
    for (int kk = 0; kk < 2; kk++) {
      bf16x8 bfr[2];
#pragma unroll
      for (int n = 0; n < 2; n++) {
        int col = wc * 32 + n * 16 + lr;
        bfr[n] = *(const bf16x8*)((const char*)Bs + col * 128 + (((kk * 4 + lg) ^ (col & 7)) << 4));
      }
#pragma unroll
      for (int m = 0; m < 4; m++) {
        int row = wr * 64 + m * 16 + lr;
        bf16x8 af = *(const bf16x8*)((const char*)As + row * 128 + (((kk * 4 + lg) ^ (row & 7)) << 4));
#pragma unroll
        for (int n = 0; n < 2; n++)
          acc[m][n] = __builtin_amdgcn_mfma_f32_16x16x32_bf16(af, bfr[n], acc[m][n], 0, 0, 0);
      }
    }
  }
#pragma unroll
  for (int m = 0; m < 4; m++)
#pragma unroll
    for (int n = 0; n < 2; n++) {
      int colg = wc * 32 + n * 16 + lr;
      int ch = ch0 + colg;
      int h = ch / 192, role = (ch >> 6) % 3, d = ch & 63;
      float bs = bias[colg];
      // q pre-scale: 1/sqrt(DH) * log2(e)  (attention works in exp2 domain)
      float qsc = (role == 0) ? 0.18033688f : 1.0f;
      int growb = row0 + wr * 64 + m * 16 + lg * 4;
      int nn = growb >> 10, ssi0 = growb & (S - 1);
      size_t nh = (size_t)(nn * HEADS + h);
      if (role == 2) {
        u16 pk[4];
#pragma unroll
        for (int r = 0; r < 4; r++) pk[r] = f2bf(acc[m][n][r] + bs);
        *(uint2*)&Vt[(nh * DH + d) * S + ssi0] = *(const uint2*)pk;
      } else {
        u16* dst = (role == 0) ? Qb : Kb;
#pragma unroll
        for (int r = 0; r < 4; r++)
          dst[(nh * S + ssi0 + r) * DH + d] = f2bf((acc[m][n][r] + bs) * qsc);
      }
    }
}

// ---------------- MFMA GEMM: proj (Obf bf16 -> out NCHW), W split hi+lo -----
__global__ __launch_bounds__(256) void gemm_proj(
    const u16* __restrict__ Aob, const u16* __restrict__ Wh, const u16* __restrict__ Wl,
    const float* __restrict__ bias, float* __restrict__ out) {
  __shared__ __attribute__((aligned(16))) u16 As[128 * 64];
  __shared__ __attribute__((aligned(16))) u16 Bh[64 * 64];
  __shared__ __attribute__((aligned(16))) u16 Bl[64 * 64];
  int t = threadIdx.x, wid = t >> 6, lane = t & 63, lr = lane & 15, lg = lane >> 4;
  int ch0 = blockIdx.x * 64, row0 = blockIdx.y * 128;
  int wc = wid & 1, wr = wid >> 1;
  f32x4 acc[2][4];
#pragma unroll
  for (int m = 0; m < 2; m++)
#pragma unroll
    for (int n = 0; n < 4; n++) acc[m][n] = (f32x4){0.f, 0.f, 0.f, 0.f};

  for (int k0 = 0; k0 < 512; k0 += 64) {
    __syncthreads();
#pragma unroll
    for (int it = 0; it < 4; it++) {
      int idx = (wid * 4 + it) * 64 + lane;
      int r = idx >> 3, sg = idx & 7;
      gl_lds16(Aob + (size_t)(row0 + r) * 512 + k0 + ((sg ^ (r & 7)) * 8),
               (char*)As + (wid * 4 + it) * 1024);
    }
#pragma unroll
    for (int it = 0; it < 2; it++) {
      int idx = (wid * 2 + it) * 64 + lane;
      int r = idx >> 3, sg = idx & 7;
      size_t go = (size_t)(ch0 + r) * 512 + k0 + ((sg ^ (r & 7)) * 8);
      gl_lds16(Wh + go, (char*)Bh + (wid * 2 + it) * 1024);
      gl_lds16(Wl + go, (char*)Bl + (wid * 2 + it) * 1024);
    }
    __syncthreads();
#pragma unroll
    for (int kk = 0; kk < 2; kk++) {
      bf16x8 ar[4];
#pragma unroll
      for (int n = 0; n < 4; n++) {
        int row = wr * 64 + n * 16 + lr;
        ar[n] = *(const bf16x8*)((const char*)As + row * 128 + (((kk * 4 + lg) ^ (row & 7)) << 4));
      }
#pragma unroll
      for (int m = 0; m < 2; m++) {
        int ch = wc * 32 + m * 16 + lr;
        bf16x8 bh = *(const bf16x8*)((const char*)Bh + ch * 128 + (((kk * 4 + lg) ^ (ch & 7)) << 4));
        bf16x8 bl = *(const bf16x8*)((const char*)Bl + ch * 128 + (((kk * 4 + lg) ^ (ch & 7)) << 4));
#pragma unroll
        for (int n = 0; n < 4; n++) {
          acc[m][n] = __builtin_amdgcn_mfma_f32_16x16x32_bf16(bh, ar[n], acc[m][n], 0, 0, 0);
          acc[m][n] = __builtin_amdgcn_mfma_f32_16x16x32_bf16(bl, ar[n], acc[m][n], 0, 0, 0);
        }
      }
    }
  }
#pragma unroll
  for (int m = 0; m < 2; m++)
#pragma unroll
    for (int n = 0; n < 4; n++) {
      int rowg = row0 + wr * 64 + n * 16 + lr;
      int nn = rowg >> 10, ssi = rowg & (S - 1);
#pragma unroll
      for (int r = 0; r < 4; r++) {
        int ch = ch0 + wc * 32 + m * 16 + lg * 4 + r;
        out[((size_t)nn * C + ch) * S + ssi] = acc[m][n][r] + bias[ch];
      }
    }
}

// ---------------- MFMA flash attention, exp2 domain, KVB=64, double-buffered
// Q pre-scaled by 0.125*log2(e) upstream. Per block: 4 waves x 16 q-rows.
constexpr int KVB = 64;

__global__ __launch_bounds__(256) void attn_kernel(
    const u16* __restrict__ Qbf, const u16* __restrict__ Kbf,
    const u16* __restrict__ Vtb, u16* __restrict__ Obf) {
  __shared__ __attribute__((aligned(16))) u16 Ks[2][KVB * DH];
  __shared__ __attribute__((aligned(16))) u16 Vs[2][DH * KVB];
  __shared__ __attribute__((aligned(16))) u16 Ps[4][16 * KVB];

  int tid = threadIdx.x;
  int wave = tid >> 6, lane = tid & 63;
  int lr = lane & 15, lg = lane >> 4;
  int w = (blockIdx.x & 7) * 128 + (blockIdx.x >> 3);
  int qt = w & 15, nh = w >> 4;
  const u16* Qg = Qbf + (size_t)nh * S * DH;
  const u16* Kg = Kbf + (size_t)nh * S * DH;
  const u16* Vg = Vtb + (size_t)nh * DH * S;

  int qrow = qt * 64 + wave * 16 + lr;
  bf16x8 qf0 = *(const bf16x8*)(Qg + (size_t)qrow * DH + lg * 8);
  bf16x8 qf1 = *(const bf16x8*)(Qg + (size_t)qrow * DH + lg * 8 + 32);

  f32x4 oacc[4];
#pragma unroll
  for (int dt = 0; dt < 4; dt++) oacc[dt] = (f32x4){0.f, 0.f, 0.f, 0.f};
  float m_run = -1e30f, l_run = 0.f;   // log2-domain stats for q = lr

  char* Pw = (char*)&Ps[wave][0];
  int e0i = tid, e1i = tid + 256;
  int r0 = e0i >> 3, sg0 = e0i & 7, r1 = e1i >> 3, sg1 = e1i & 7;
  char* kd0 = (char*)&Ks[0][0] + (e0i & ~63) * 16;
  char* kd1 = (char*)&Ks[0][0] + (e1i & ~63) * 16;
  char* vd0 = (char*)&Vs[0][0] + (e0i & ~63) * 16;
  char* vd1 = (char*)&Vs[0][0] + (e1i & ~63) * 16;

#define STAGE(kb, b)                                                             \
  do {                                                                           \
    gl_lds16(Kg + (size_t)((kb) * KVB + r0) * 64 + ((sg0 ^ (r0 & 7)) * 8),       \
             kd0 + (b) * (KVB * DH * 2));                                        \
    gl_lds16(Kg + (size_t)((kb) * KVB + r1) * 64 + ((sg1 ^ (r1 & 7)) * 8),       \
             kd1 + (b) * (KVB * DH * 2));                                        \
    gl_lds16(Vg + (size_t)r0 * S + (kb) * KVB + ((sg0 ^ (r0 & 7)) * 8),          \
             vd0 + (b) * (KVB * DH * 2));                                        \
    gl_lds16(Vg + (size_t)r1 * S + (kb) * KVB + ((sg1 ^ (r1 & 7)) * 8),          \
             vd1 + (b) * (KVB * DH * 2));                                        \
  } while (0)

  STAGE(0, 0);

  for (int kb = 0; kb < S / KVB; kb++) {
    int cur = kb & 1;
    __syncthreads();
    if (kb + 1 < S / KVB) STAGE(kb + 1, cur ^ 1);

    const char* Kc = (const char*)&Ks[cur][0];
    const char* Vc = (const char*)&Vs[cur][0];

    // QK^T (swapped): lane owns q-row lr; sc[t] covers keys t*16+lg*4..+3
    f32x4 sc[4];
    __builtin_amdgcn_s_setprio(1);
#pragma unroll
    for (int t = 0; t < 4; t++) {
      int key = t * 16 + lr;
      const char* kr = Kc + key * 128;
      bf16x8 kf0 = *(const bf16x8*)(kr + ((lg * 16) ^ ((lr & 7) << 4)));
      bf16x8 kf1 = *(const bf16x8*)(kr + (((lg * 16) + 64) ^ ((lr & 7) << 4)));
      f32x4 z = (f32x4){0.f, 0.f, 0.f, 0.f};
      z = __builtin_amdgcn_mfma_f32_16x16x32_bf16(kf0, qf0, z, 0, 0, 0);
      sc[t] = __builtin_amdgcn_mfma_f32_16x16x32_bf16(kf1, qf1, z, 0, 0, 0);
    }
    __builtin_amdgcn_s_setprio(0);

    float pmax = -1e30f;
#pragma unroll
    for (int t = 0; t < 4; t++) {
      float a = fmaxf(fmaxf(sc[t][0], sc[t][1]), fmaxf(sc[t][2], sc[t][3]));
      pmax = fmaxf(pmax, a);
    }
    pmax = fmaxf(pmax, __shfl_xor(pmax, 16));
    pmax = fmaxf(pmax, __shfl_xor(pmax, 32));

    // defer-max: 11.5 log2-units = 8 nats
    if (!__all(pmax <= m_run + 11.5f)) {
      float mnew = fmaxf(m_run, pmax);
      float corr = exp2f(m_run - mnew);
      m_run = mnew;
      l_run *= corr;
      float cr[4];
#pragma unroll
      for (int r = 0; r < 4; r++) cr[r] = __shfl(corr, lg * 4 + r);
#pragma unroll
      for (int dt = 0; dt < 4; dt++)
#pragma unroll
        for (int r = 0; r < 4; r++) oacc[dt][r] *= cr[r];
    }

    float psum = 0.f;
#pragma unroll
    for (int t = 0; t < 4; t++) {
      float e0 = exp2f(sc[t][0] - m_run);
      float e1 = exp2f(sc[t][1] - m_run);
      float e2 = exp2f(sc[t][2] - m_run);
      float e3 = exp2f(sc[t][3] - m_run);
      psum += (e0 + e1) + (e2 + e3);
      uint2 pw; pw.x = cvtpk(e0, e1); pw.y = cvtpk(e2, e3);
      *(uint2*)(Pw + lr * 128 + ((t * 32 + lg * 8) ^ ((lr & 7) << 4))) = pw;
    }
    psum += __shfl_xor(psum, 16);
    psum += __shfl_xor(psum, 32);
    l_run += psum;

    // PV: O += P(16x64) x V(64x64)
    __builtin_amdgcn_s_setprio(1);
#pragma unroll
    for (int kk = 0; kk < 2; kk++) {
      bf16x8 pf = *(const bf16x8*)(Pw + lr * 128 + ((kk * 64 + lg * 16) ^ ((lr & 7) << 4)));
#pragma unroll
      for (int dt = 0; dt < 4; dt++) {
        int dd = dt * 16 + lr;
        bf16x8 vf = *(const bf16x8*)(Vc + dd * 128 + ((kk * 64 + lg * 16) ^ ((lr & 7) << 4)));
        oacc[dt] = __builtin_amdgcn_mfma_f32_16x16x32_bf16(pf, vf, oacc[dt], 0, 0, 0);
      }
    }
    __builtin_amdgcn_s_setprio(0);
  }
#undef STAGE

  int n = nh >> 3, h = nh & 7;
  float lf[4];
#pragma unroll
  for (int r = 0; r < 4; r++) lf[r] = 1.0f / __shfl(l_run, lg * 4 + r);
#pragma unroll
  for (int dt = 0; dt < 4; dt++)
#pragma unroll
    for (int r = 0; r < 4; r++) {
      int q = qt * 64 + wave * 16 + lg * 4 + r;
      int d = dt * 16 + lr;
      Obf[((size_t)n * S + q) * C + h * DH + d] = f2bf(oacc[dt][r] * lf[r]);
    }
}

}  // namespace

extern "C" void kernel_launch(void* const* d_in, const int* in_sizes, int n_in,
                              void* d_out, int out_size, void* d_ws, size_t ws_size,
                              hipStream_t stream) {
  const float* x       = (const float*)d_in[0];
  const float* qx      = (const float*)d_in[1];
  const float* q_ln_g  = (const float*)d_in[2];
  const float* q_ln_b  = (const float*)d_in[3];
  const float* q_w     = (const float*)d_in[4];
  const float* q_b     = (const float*)d_in[5];
  const float* kv_ln_g = (const float*)d_in[6];
  const float* kv_ln_b = (const float*)d_in[7];
  const float* kv_w    = (const float*)d_in[8];
  const float* kv_b    = (const float*)d_in[9];
  const float* proj_w  = (const float*)d_in[10];
  const float* proj_b  = (const float*)d_in[11];
  float* out = (float*)d_out;

  float* ws = (float*)d_ws;
  float* mu_x = ws;
  float* rs_x = ws + RTOT;
  float* mu_q = ws + 2 * RTOT;
  float* rs_q = ws + 3 * RTOT;
  u16* u = (u16*)(ws + 4 * RTOT);
  u16* Xkv  = u;                u += (size_t)RTOT * C;
  u16* Xq   = u;                u += (size_t)RTOT * C;
  u16* Wtq  = u;                u += (size_t)C * C;
  u16* Wtkv = u;                u += (size_t)2 * C * C;
  u16* Wph  = u;                u += (size_t)C * C;
  u16* Wpl  = u;                u += (size_t)C * C;
  u16* Qb   = u;                u += (size_t)NBATCH * HEADS * S * DH;
  u16* Kb   = u;                u += (size_t)NBATCH * HEADS * S * DH;
  u16* Vt   = u;                u += (size_t)NBATCH * HEADS * S * DH;
  u16* Obf  = u;

  hipLaunchKernelGGL(ln_stats_kernel, dim3(RTOT / 64, 2), dim3(256), 0, stream,
                     x, qx, mu_x, rs_x, mu_q, rs_q);
  hipLaunchKernelGGL(ln_apply_tr, dim3(S / 64, C / 64, 2 * NBATCH), dim3(256), 0, stream,
                     x, qx, mu_x, rs_x, mu_q, rs_q,
                     kv_ln_g, kv_ln_b, q_ln_g, q_ln_b, Xkv, Xq);
  hipLaunchKernelGGL(prep_w, dim3(8, 16, 3), dim3(256), 0, stream,
                     q_w, kv_w, proj_w, Wtq, Wtkv, Wph, Wpl);
  hipLaunchKernelGGL(gemm_qkv, dim3(24, RTOT / 128), dim3(256), 0, stream,
                     Xq, Xkv, Wtq, Wtkv, q_b, kv_b, Qb, Kb, Vt);
  hipLaunchKernelGGL(attn_kernel, dim3(1024), dim3(256), 0, stream,
                     Qb, Kb, Vt, Obf);
  hipLaunchKernelGGL(gemm_proj, dim3(C / 64, RTOT / 128), dim3(256), 0, stream,
                     Obf, Wph, Wpl, proj_b, out);
}

// Round 6
// 99.379 us; speedup vs baseline: 29.0143x; 1.0686x over previous
//
#include <hip/hip_runtime.h>
#include <math.h>

namespace {

constexpr int S = 1024;
constexpr int C = 512;
constexpr int NBATCH = 8;
constexpr int RTOT = NBATCH * S;  // 8192
constexpr int HEADS = 8;
constexpr int DH = 64;

typedef __attribute__((ext_vector_type(8))) short bf16x8;
typedef __attribute__((ext_vector_type(4))) float f32x4;
typedef unsigned short u16;
typedef unsigned int u32;

__device__ __forceinline__ u16 f2bf(float x) {
  union { float f; u32 u; } v; v.f = x;
  u32 r = v.u + 0x7FFF + ((v.u >> 16) & 1);
  return (u16)(r >> 16);
}
__device__ __forceinline__ float bf2f(u16 b) {
  union { u32 u; float f; } v; v.u = (u32)b << 16; return v.f;
}
__device__ __forceinline__ void gl_lds16(const void* g, void* l) {
  auto gp = (const __attribute__((address_space(1))) u32*)g;
  auto lp = (__attribute__((address_space(3))) u32*)l;
  __builtin_amdgcn_global_load_lds(gp, lp, 16, 0, 0);
}

// ---------------- Fused LN: stats + apply + NCHW->(row,c) transpose + bf16 --
// block = 32 si rows x full 512 c, one (n, stream); stats pass then L2-hot apply
__global__ void ln_fused(const float* __restrict__ x, const float* __restrict__ qx,
                         const float* __restrict__ gx, const float* __restrict__ bx,
                         const float* __restrict__ gq, const float* __restrict__ bq,
                         u16* __restrict__ Xkv, u16* __restrict__ Xq) {
  __shared__ float Ssum[8][32], Ssq[8][32];
  __shared__ float mu_s[32], rs_s[32];
  __shared__ float T[32][65];
  int t = threadIdx.x;
  int si0 = blockIdx.x * 32;
  int isq = blockIdx.y & 1, n = blockIdx.y >> 1;
  const float* in = isq ? qx : x;
  const float* g  = isq ? gq : gx;
  const float* be = isq ? bq : bx;
  u16* out = isq ? Xq : Xkv;

  // stats: each thread sums 64 channels for one si
  {
    int sl = t & 31, cg = t >> 5;
    const float* p = in + ((size_t)n * C + cg * 64) * S + si0 + sl;
    float s = 0.f, sq = 0.f;
#pragma unroll 8
    for (int c = 0; c < 64; c++) { float v = p[(size_t)c * S]; s += v; sq += v * v; }
    Ssum[cg][sl] = s; Ssq[cg][sl] = sq;
  }
  __syncthreads();
  if (t < 32) {
    float ss = 0.f, q2 = 0.f;
#pragma unroll
    for (int i = 0; i < 8; i++) { ss += Ssum[i][t]; q2 += Ssq[i][t]; }
    float m = ss * (1.0f / C);
    float var = q2 * (1.0f / C) - m * m;
    mu_s[t] = m; rs_s[t] = rsqrtf(var + 1e-5f);
  }
  __syncthreads();

  int si4 = (t & 7) * 4, cl = t >> 3;          // load/transpose idx
  float4 mu4 = *(const float4*)&mu_s[si4];
  float4 rs4 = *(const float4*)&rs_s[si4];
  int wsl = t >> 3, wc8 = (t & 7) * 8;          // write idx

  for (int c0 = 0; c0 < C; c0 += 64) {
#pragma unroll
    for (int i = 0; i < 2; i++) {
      int c = c0 + cl + i * 32;
      float4 v = *(const float4*)&in[((size_t)n * C + c) * S + si0 + si4];
      float gg = g[c], bb = be[c];
      T[si4 + 0][cl + i * 32] = (v.x - mu4.x) * rs4.x * gg + bb;
      T[si4 + 1][cl + i * 32] = (v.y - mu4.y) * rs4.y * gg + bb;
      T[si4 + 2][cl + i * 32] = (v.z - mu4.z) * rs4.z * gg + bb;
      T[si4 + 3][cl + i * 32] = (v.w - mu4.w) * rs4.w * gg + bb;
    }
    __syncthreads();
    u16 pk[8];
#pragma unroll
    for (int j = 0; j < 8; j++) pk[j] = f2bf(T[wsl][wc8 + j]);
    *(uint4*)&out[((size_t)(n * S + si0 + wsl)) * C + c0 + wc8] = *(const uint4*)pk;
    __syncthreads();
  }
}

// ---------------- Weight prep: W[k][col] -> Wt[col][k] bf16 (+split for proj)
__global__ void prep_w(const float* __restrict__ qw, const float* __restrict__ kvw,
                       const float* __restrict__ pw,
                       u16* __restrict__ Wtq, u16* __restrict__ Wtkv,
                       u16* __restrict__ Wph, u16* __restrict__ Wpl) {
  int z = blockIdx.z;
  int N = (z == 1) ? 1024 : 512;
  int col0 = blockIdx.y * 64;
  if (col0 >= N) return;
  int k0 = blockIdx.x * 64;
  const float* W = (z == 0) ? qw : (z == 1) ? kvw : pw;
  __shared__ float T[64][65];
  int t = threadIdx.x;
  int kl = t >> 4, c4 = (t & 15) * 4;
#pragma unroll
  for (int i = 0; i < 4; i++) {
    float4 v = *(const float4*)&W[(size_t)(k0 + kl + i * 16) * N + col0 + c4];
    T[kl + i * 16][c4 + 0] = v.x; T[kl + i * 16][c4 + 1] = v.y;
    T[kl + i * 16][c4 + 2] = v.z; T[kl + i * 16][c4 + 3] = v.w;
  }
  __syncthreads();
#pragma unroll
  for (int p = 0; p < 2; p++) {
    int cl = (t >> 3) + p * 32, k8 = (t & 7) * 8;
    u16 hi[8], lo[8];
#pragma unroll
    for (int j = 0; j < 8; j++) {
      float f = T[k8 + j][cl];
      u16 hv = f2bf(f);
      hi[j] = hv;
      lo[j] = f2bf(f - bf2f(hv));
    }
    size_t o = (size_t)(col0 + cl) * 512 + k0 + k8;
    if (z == 0) *(uint4*)&Wtq[o] = *(const uint4*)hi;
    else if (z == 1) *(uint4*)&Wtkv[o] = *(const uint4*)hi;
    else { *(uint4*)&Wph[o] = *(const uint4*)hi; *(uint4*)&Wpl[o] = *(const uint4*)lo; }
  }
}

// ---------------- MFMA GEMM: merged q+kv projection, 128x128 tile -----------
// grid (12, 64): colb<4 -> q cols, colb>=4 -> kv cols
__global__ __launch_bounds__(256, 4) void gemm_qkv(
    const u16* __restrict__ Xq, const u16* __restrict__ Xkv,
    const u16* __restrict__ Wtq, const u16* __restrict__ Wtkv,
    const float* __restrict__ q_b, const float* __restrict__ kv_b,
    u16* __restrict__ Qb, u16* __restrict__ Kb, u16* __restrict__ Vt) {
  __shared__ __attribute__((aligned(16))) u16 As[128 * 64];
  __shared__ __attribute__((aligned(16))) u16 Bs[128 * 64];
  int t = threadIdx.x, wid = t >> 6, lane = t & 63, lr = lane & 15, lg = lane >> 4;
  int colb = blockIdx.x;
  const u16* A; const u16* Wt; const float* bias; int ch0;
  if (colb < 4) { A = Xq;  Wt = Wtq  + (size_t)colb * 128 * 512;       bias = q_b  + colb * 128;       ch0 = colb * 128; }
  else          { A = Xkv; Wt = Wtkv + (size_t)(colb - 4) * 128 * 512; bias = kv_b + (colb - 4) * 128; ch0 = 512 + (colb - 4) * 128; }
  int row0 = blockIdx.y * 128;
  int wr = wid >> 1, wc = wid & 1;   // wave: 64 rows x 64 cols
  f32x4 acc[4][4];
#pragma unroll
  for (int m = 0; m < 4; m++)
#pragma unroll
    for (int n = 0; n < 4; n++) acc[m][n] = (f32x4){0.f, 0.f, 0.f, 0.f};

  for (int k0 = 0; k0 < 512; k0 += 64) {
    __syncthreads();
#pragma unroll
    for (int it = 0; it < 4; it++) {
      int chunk = (wid * 4 + it) * 64 + lane;
      int r = chunk >> 3, sg = chunk & 7;
      gl_lds16(A + (size_t)(row0 + r) * 512 + k0 + ((sg ^ (r & 7)) * 8),
               (char*)As + (size_t)chunk * 16);
    }
#pragma unroll
    for (int it = 0; it < 4; it++) {
      int chunk = (wid * 4 + it) * 64 + lane;
      int r = chunk >> 3, sg = chunk & 7;
      gl_lds16(Wt + (size_t)r * 512 + k0 + ((sg ^ (r & 7)) * 8),
               (char*)Bs + (size_t)chunk * 16);
    }
    __syncthreads();
#pragma unroll
    for (int kk = 0; kk < 2; kk++) {
      bf16x8 bfr[4];
#pragma unroll
      for (int n = 0; n < 4; n++) {
        int col = wc * 64 + n * 16 + lr;
        bfr[n] = *(const bf16x8*)((const char*)Bs + col * 128 + (((kk * 4 + lg) ^ (col & 7)) << 4));
      }
#pragma unroll
      for (int m = 0; m < 4; m++) {
        int row = wr * 64 + m * 16 + lr;
        bf16x8 af = *(const bf16x8*)((const char*)As + row * 128 + (((kk * 4 + lg) ^ (row & 7)) << 4));
#pragma unroll
        for (int n = 0; n < 4; n++)
          acc[m][n] = __builtin_amdgcn_mfma_f32_16x16x32_bf16(af, bfr[n], acc[m][n], 0, 0, 0);
      }
    }
  }
#pragma unroll
  for (int m = 0; m < 4; m++)
#pragma unroll
    for (int n = 0; n < 4; n++) {
      int colg = wc * 64 + n * 16 + lr;
      int ch = ch0 + colg;
      int h = ch / 192, role = (ch >> 6) % 3, d = ch & 63;
      float bs = bias[colg];
      // q pre-scale: 1/sqrt(DH) * log2(e)  (attention works in exp2 domain)
      float qsc = (role == 0) ? 0.18033688f : 1.0f;
      int growb = row0 + wr * 64 + m * 16 + lg * 4;
      int nn = growb >> 10, ssi0 = growb & (S - 1);
      size_t nh = (size_t)(nn * HEADS + h);
      if (role == 2) {
        u16 pk[4];
#pragma unroll
        for (int r = 0; r < 4; r++) pk[r] = f2bf(acc[m][n][r] + bs);
        *(uint2*)&Vt[(nh * DH + d) * S + ssi0] = *(const uint2*)pk;
      } else {
        u16* dst = (role == 0) ? Qb : Kb;
#pragma unroll
        for (int r = 0; r < 4; r++)
          dst[(nh * S + ssi0 + r) * DH + d] = f2bf((acc[m][n][r] + bs) * qsc);
      }
    }
}

// ---------------- MFMA GEMM: proj (Obf bf16 -> out NCHW), W split hi+lo -----
__global__ __launch_bounds__(256) void gemm_proj(
    const u16* __restrict__ Aob, const u16* __restrict__ Wh, const u16* __restrict__ Wl,
    const float* __restrict__ bias, float* __restrict__ out) {
  __shared__ __attribute__((aligned(16))) u16 As[128 * 64];
  __shared__ __attribute__((aligned(16))) u16 Bh[64 * 64];
  __shared__ __attribute__((aligned(16))) u16 Bl[64 * 64];
  int t = threadIdx.x, wid = t >> 6, lane = t & 63, lr = lane & 15, lg = lane >> 4;
  int ch0 = blockIdx.x * 64, row0 = blockIdx.y * 128;
  int wc = wid & 1, wr = wid >> 1;
  f32x4 acc[2][4];
#pragma unroll
  for (int m = 0; m < 2; m++)
#pragma unroll
    for (int n = 0; n < 4; n++) acc[m][n] = (f32x4){0.f, 0.f, 0.f, 0.f};

  for (int k0 = 0; k0 < 512; k0 += 64) {
    __syncthreads();
#pragma unroll
    for (int it = 0; it < 4; it++) {
      int idx = (wid * 4 + it) * 64 + lane;
      int r = idx >> 3, sg = idx & 7;
      gl_lds16(Aob + (size_t)(row0 + r) * 512 + k0 + ((sg ^ (r & 7)) * 8),
               (char*)As + (wid * 4 + it) * 1024);
    }
#pragma unroll
    for (int it = 0; it < 2; it++) {
      int idx = (wid * 2 + it) * 64 + lane;
      int r = idx >> 3, sg = idx & 7;
      size_t go = (size_t)(ch0 + r) * 512 + k0 + ((sg ^ (r & 7)) * 8);
      gl_lds16(Wh + go, (char*)Bh + (wid * 2 + it) * 1024);
      gl_lds16(Wl + go, (char*)Bl + (wid * 2 + it) * 1024);
    }
    __syncthreads();
#pragma unroll
    for (int kk = 0; kk < 2; kk++) {
      bf16x8 ar[4];
#pragma unroll
      for (int n = 0; n < 4; n++) {
        int row = wr * 64 + n * 16 + lr;
        ar[n] = *(const bf16x8*)((const char*)As + row * 128 + (((kk * 4 + lg) ^ (row & 7)) << 4));
      }
#pragma unroll
      for (int m = 0; m < 2; m++) {
        int ch = wc * 32 + m * 16 + lr;
        bf16x8 bh = *(const bf16x8*)((const char*)Bh + ch * 128 + (((kk * 4 + lg) ^ (ch & 7)) << 4));
        bf16x8 bl = *(const bf16x8*)((const char*)Bl + ch * 128 + (((kk * 4 + lg) ^ (ch & 7)) << 4));
#pragma unroll
        for (int n = 0; n < 4; n++) {
          acc[m][n] = __builtin_amdgcn_mfma_f32_16x16x32_bf16(bh, ar[n], acc[m][n], 0, 0, 0);
          acc[m][n] = __builtin_amdgcn_mfma_f32_16x16x32_bf16(bl, ar[n], acc[m][n], 0, 0, 0);
        }
      }
    }
  }
#pragma unroll
  for (int m = 0; m < 2; m++)
#pragma unroll
    for (int n = 0; n < 4; n++) {
      int rowg = row0 + wr * 64 + n * 16 + lr;
      int nn = rowg >> 10, ssi = rowg & (S - 1);
#pragma unroll
      for (int r = 0; r < 4; r++) {
        int ch = ch0 + wc * 32 + m * 16 + lg * 4 + r;
        out[((size_t)nn * C + ch) * S + ssi] = acc[m][n][r] + bias[ch];
      }
    }
}

// ---------------- MFMA flash attention, exp2 domain, l via MFMA --------------
constexpr int KVB = 64;

__global__ __launch_bounds__(256, 4) void attn_kernel(
    const u16* __restrict__ Qbf, const u16* __restrict__ Kbf,
    const u16* __restrict__ Vtb, u16* __restrict__ Obf) {
  __shared__ __attribute__((aligned(16))) u16 Ks[2][KVB * DH];
  __shared__ __attribute__((aligned(16))) u16 Vs[2][DH * KVB];
  __shared__ __attribute__((aligned(16))) u16 Ps[4][16 * KVB];

  int tid = threadIdx.x;
  int wave = tid >> 6, lane = tid & 63;
  int lr = lane & 15, lg = lane >> 4;
  int w = (blockIdx.x & 7) * 128 + (blockIdx.x >> 3);
  int qt = w & 15, nh = w >> 4;
  const u16* Qg = Qbf + (size_t)nh * S * DH;
  const u16* Kg = Kbf + (size_t)nh * S * DH;
  const u16* Vg = Vtb + (size_t)nh * DH * S;

  int qrow = qt * 64 + wave * 16 + lr;
  bf16x8 qf0 = *(const bf16x8*)(Qg + (size_t)qrow * DH + lg * 8);
  bf16x8 qf1 = *(const bf16x8*)(Qg + (size_t)qrow * DH + lg * 8 + 32);

  bf16x8 ones;
#pragma unroll
  for (int i = 0; i < 8; i++) ones[i] = (short)0x3F80;   // bf16 1.0

  f32x4 oacc[4], lacc;
#pragma unroll
  for (int dt = 0; dt < 4; dt++) oacc[dt] = (f32x4){0.f, 0.f, 0.f, 0.f};
  lacc = (f32x4){0.f, 0.f, 0.f, 0.f};
  float m_run = -1e30f;   // log2-domain running max for q = lr

  char* Pw = (char*)&Ps[wave][0];
  int e0i = tid, e1i = tid + 256;
  int r0 = e0i >> 3, sg0 = e0i & 7, r1 = e1i >> 3, sg1 = e1i & 7;
  char* kd0 = (char*)&Ks[0][0] + (e0i & ~63) * 16;
  char* kd1 = (char*)&Ks[0][0] + (e1i & ~63) * 16;
  char* vd0 = (char*)&Vs[0][0] + (e0i & ~63) * 16;
  char* vd1 = (char*)&Vs[0][0] + (e1i & ~63) * 16;

#define STAGE(kb, b)                                                             \
  do {                                                                           \
    gl_lds16(Kg + (size_t)((kb) * KVB + r0) * 64 + ((sg0 ^ (r0 & 7)) * 8),       \
             kd0 + (b) * (KVB * DH * 2));                                        \
    gl_lds16(Kg + (size_t)((kb) * KVB + r1) * 64 + ((sg1 ^ (r1 & 7)) * 8),       \
             kd1 + (b) * (KVB * DH * 2));                                        \
    gl_lds16(Vg + (size_t)r0 * S + (kb) * KVB + ((sg0 ^ (r0 & 7)) * 8),          \
             vd0 + (b) * (KVB * DH * 2));                                        \
    gl_lds16(Vg + (size_t)r1 * S + (kb) * KVB + ((sg1 ^ (r1 & 7)) * 8),          \
             vd1 + (b) * (KVB * DH * 2));                                        \
  } while (0)

  STAGE(0, 0);

  for (int kb = 0; kb < S / KVB; kb++) {
    int cur = kb & 1;
    __syncthreads();
    if (kb + 1 < S / KVB) STAGE(kb + 1, cur ^ 1);

    const char* Kc = (const char*)&Ks[cur][0];
    const char* Vc = (const char*)&Vs[cur][0];

    // QK^T (swapped): lane owns q-row lr; sc[t] covers keys t*16+lg*4..+3
    f32x4 sc[4];
#pragma unroll
    for (int t = 0; t < 4; t++) {
      int key = t * 16 + lr;
      const char* kr = Kc + key * 128;
      bf16x8 kf0 = *(const bf16x8*)(kr + ((lg * 16) ^ ((lr & 7) << 4)));
      bf16x8 kf1 = *(const bf16x8*)(kr + (((lg * 16) + 64) ^ ((lr & 7) << 4)));
      f32x4 z = (f32x4){0.f, 0.f, 0.f, 0.f};
      z = __builtin_amdgcn_mfma_f32_16x16x32_bf16(kf0, qf0, z, 0, 0, 0);
      sc[t] = __builtin_amdgcn_mfma_f32_16x16x32_bf16(kf1, qf1, z, 0, 0, 0);
    }

    float pmax = -1e30f;
#pragma unroll
    for (int t = 0; t < 4; t++) {
      float a = fmaxf(fmaxf(sc[t][0], sc[t][1]), fmaxf(sc[t][2], sc[t][3]));
      pmax = fmaxf(pmax, a);
    }
    pmax = fmaxf(pmax, __shfl_xor(pmax, 16));
    pmax = fmaxf(pmax, __shfl_xor(pmax, 32));

    // defer-max: 11.5 log2-units = 8 nats
    if (!__all(pmax <= m_run + 11.5f)) {
      float mnew = fmaxf(m_run, pmax);
      float corr = exp2f(m_run - mnew);
      m_run = mnew;
      float cr[4];
#pragma unroll
      for (int r = 0; r < 4; r++) cr[r] = __shfl(corr, lg * 4 + r);
#pragma unroll
      for (int r = 0; r < 4; r++) lacc[r] *= cr[r];
#pragma unroll
      for (int dt = 0; dt < 4; dt++)
#pragma unroll
        for (int r = 0; r < 4; r++) oacc[dt][r] *= cr[r];
    }

    // exp2, pack to bf16, write P
#pragma unroll
    for (int t = 0; t < 4; t++) {
      float e0 = exp2f(sc[t][0] - m_run);
      float e1 = exp2f(sc[t][1] - m_run);
      float e2 = exp2f(sc[t][2] - m_run);
      float e3 = exp2f(sc[t][3] - m_run);
      uint2 pw;
      pw.x = (u32)f2bf(e0) | ((u32)f2bf(e1) << 16);
      pw.y = (u32)f2bf(e2) | ((u32)f2bf(e3) << 16);
      *(uint2*)(Pw + lr * 128 + ((t * 32 + lg * 8) ^ ((lr & 7) << 4))) = pw;
    }

    // PV: O += P(16x64) x V(64x64); l += P x 1s  (row-sum on the MFMA pipe)
#pragma unroll
    for (int kk = 0; kk < 2; kk++) {
      bf16x8 pf = *(const bf16x8*)(Pw + lr * 128 + ((kk * 64 + lg * 16) ^ ((lr & 7) << 4)));
      lacc = __builtin_amdgcn_mfma_f32_16x16x32_bf16(pf, ones, lacc, 0, 0, 0);
#pragma unroll
      for (int dt = 0; dt < 4; dt++) {
        int dd = dt * 16 + lr;
        bf16x8 vf = *(const bf16x8*)(Vc + dd * 128 + ((kk * 64 + lg * 16) ^ ((lr & 7) << 4)));
        oacc[dt] = __builtin_amdgcn_mfma_f32_16x16x32_bf16(pf, vf, oacc[dt], 0, 0, 0);
      }
    }
  }
#undef STAGE

  // epilogue: lacc[r] is l for q-row lg*4+r (replicated across cols) — no shfl
  int n = nh >> 3, h = nh & 7;
  float lf[4];
#pragma unroll
  for (int r = 0; r < 4; r++) lf[r] = 1.0f / lacc[r];
#pragma unroll
  for (int dt = 0; dt < 4; dt++)
#pragma unroll
    for (int r = 0; r < 4; r++) {
      int q = qt * 64 + wave * 16 + lg * 4 + r;
      int d = dt * 16 + lr;
      Obf[((size_t)n * S + q) * C + h * DH + d] = f2bf(oacc[dt][r] * lf[r]);
    }
}

}  // namespace

extern "C" void kernel_launch(void* const* d_in, const int* in_sizes, int n_in,
                              void* d_out, int out_size, void* d_ws, size_t ws_size,
                              hipStream_t stream) {
  const float* x       = (const float*)d_in[0];
  const float* qx      = (const float*)d_in[1];
  const float* q_ln_g  = (const float*)d_in[2];
  const float* q_ln_b  = (const float*)d_in[3];
  const float* q_w     = (const float*)d_in[4];
  const float* q_b     = (const float*)d_in[5];
  const float* kv_ln_g = (const float*)d_in[6];
  const float* kv_ln_b = (const float*)d_in[7];
  const float* kv_w    = (const float*)d_in[8];
  const float* kv_b    = (const float*)d_in[9];
  const float* proj_w  = (const float*)d_in[10];
  const float* proj_b  = (const float*)d_in[11];
  float* out = (float*)d_out;

  u16* u = (u16*)d_ws;
  u16* Xkv  = u;                u += (size_t)RTOT * C;
  u16* Xq   = u;                u += (size_t)RTOT * C;
  u16* Wtq  = u;                u += (size_t)C * C;
  u16* Wtkv = u;                u += (size_t)2 * C * C;
  u16* Wph  = u;                u += (size_t)C * C;
  u16* Wpl  = u;                u += (size_t)C * C;
  u16* Qb   = u;                u += (size_t)NBATCH * HEADS * S * DH;
  u16* Kb   = u;                u += (size_t)NBATCH * HEADS * S * DH;
  u16* Vt   = u;                u += (size_t)NBATCH * HEADS * S * DH;
  u16* Obf  = u;

  hipLaunchKernelGGL(ln_fused, dim3(S / 32, 2 * NBATCH), dim3(256), 0, stream,
                     x, qx, kv_ln_g, kv_ln_b, q_ln_g, q_ln_b, Xkv, Xq);
  hipLaunchKernelGGL(prep_w, dim3(8, 16, 3), dim3(256), 0, stream,
                     q_w, kv_w, proj_w, Wtq, Wtkv, Wph, Wpl);
  hipLaunchKernelGGL(gemm_qkv, dim3(12, RTOT / 128), dim3(256), 0, stream,
                     Xq, Xkv, Wtq, Wtkv, q_b, kv_b, Qb, Kb, Vt);
  hipLaunchKernelGGL(attn_kernel, dim3(1024), dim3(256), 0, stream,
                     Qb, Kb, Vt, Obf);
  hipLaunchKernelGGL(gemm_proj, dim3(C / 64, RTOT / 128), dim3(256), 0, stream,
                     Obf, Wph, Wpl, proj_b, out);
}

// Round 8
// 98.534 us; speedup vs baseline: 29.2630x; 1.0086x over previous
//
#include <hip/hip_runtime.h>
#include <math.h>

namespace {

constexpr int S = 1024;
constexpr int C = 512;
constexpr int NBATCH = 8;
constexpr int RTOT = NBATCH * S;  // 8192
constexpr int HEADS = 8;
constexpr int DH = 64;

typedef __attribute__((ext_vector_type(8))) short bf16x8;
typedef __attribute__((ext_vector_type(4))) float f32x4;
typedef __attribute__((ext_vector_type(16))) float f32x16;
typedef unsigned short u16;
typedef unsigned int u32;

__device__ __forceinline__ u16 f2bf(float x) {
  union { float f; u32 u; } v; v.f = x;
  u32 r = v.u + 0x7FFF + ((v.u >> 16) & 1);
  return (u16)(r >> 16);
}
__device__ __forceinline__ float bf2f(u16 b) {
  union { u32 u; float f; } v; v.u = (u32)b << 16; return v.f;
}
__device__ __forceinline__ u32 cvtpk(float a, float b) {  // lo=a, hi=b (RTNE)
  u32 r;
  asm("v_cvt_pk_bf16_f32 %0, %1, %2" : "=v"(r) : "v"(a), "v"(b));
  return r;
}
__device__ __forceinline__ void gl_lds16(const void* g, void* l) {
  auto gp = (const __attribute__((address_space(1))) u32*)g;
  auto lp = (__attribute__((address_space(3))) u32*)l;
  __builtin_amdgcn_global_load_lds(gp, lp, 16, 0, 0);
}

// ---------------- Fused LN: stats + apply + NCHW->(row,c) transpose + bf16 --
__global__ void ln_fused(const float* __restrict__ x, const float* __restrict__ qx,
                         const float* __restrict__ gx, const float* __restrict__ bx,
                         const float* __restrict__ gq, const float* __restrict__ bq,
                         u16* __restrict__ Xkv, u16* __restrict__ Xq) {
  __shared__ float Ssum[8][32], Ssq[8][32];
  __shared__ float mu_s[32], rs_s[32];
  __shared__ float T[32][65];
  int t = threadIdx.x;
  int si0 = blockIdx.x * 32;
  int isq = blockIdx.y & 1, n = blockIdx.y >> 1;
  const float* in = isq ? qx : x;
  const float* g  = isq ? gq : gx;
  const float* be = isq ? bq : bx;
  u16* out = isq ? Xq : Xkv;

  {
    int sl = t & 31, cg = t >> 5;
    const float* p = in + ((size_t)n * C + cg * 64) * S + si0 + sl;
    float s = 0.f, sq = 0.f;
#pragma unroll 8
    for (int c = 0; c < 64; c++) { float v = p[(size_t)c * S]; s += v; sq += v * v; }
    Ssum[cg][sl] = s; Ssq[cg][sl] = sq;
  }
  __syncthreads();
  if (t < 32) {
    float ss = 0.f, q2 = 0.f;
#pragma unroll
    for (int i = 0; i < 8; i++) { ss += Ssum[i][t]; q2 += Ssq[i][t]; }
    float m = ss * (1.0f / C);
    float var = q2 * (1.0f / C) - m * m;
    mu_s[t] = m; rs_s[t] = rsqrtf(var + 1e-5f);
  }
  __syncthreads();

  int si4 = (t & 7) * 4, cl = t >> 3;
  float4 mu4 = *(const float4*)&mu_s[si4];
  float4 rs4 = *(const float4*)&rs_s[si4];
  int wsl = t >> 3, wc8 = (t & 7) * 8;

  for (int c0 = 0; c0 < C; c0 += 64) {
#pragma unroll
    for (int i = 0; i < 2; i++) {
      int c = c0 + cl + i * 32;
      float4 v = *(const float4*)&in[((size_t)n * C + c) * S + si0 + si4];
      float gg = g[c], bb = be[c];
      T[si4 + 0][cl + i * 32] = (v.x - mu4.x) * rs4.x * gg + bb;
      T[si4 + 1][cl + i * 32] = (v.y - mu4.y) * rs4.y * gg + bb;
      T[si4 + 2][cl + i * 32] = (v.z - mu4.z) * rs4.z * gg + bb;
      T[si4 + 3][cl + i * 32] = (v.w - mu4.w) * rs4.w * gg + bb;
    }
    __syncthreads();
    u16 pk[8];
#pragma unroll
    for (int j = 0; j < 8; j++) pk[j] = f2bf(T[wsl][wc8 + j]);
    *(uint4*)&out[((size_t)(n * S + si0 + wsl)) * C + c0 + wc8] = *(const uint4*)pk;
    __syncthreads();
  }
}

// ---------------- Weight prep: W[k][col] -> Wt[col][k] bf16 (+split for proj)
__global__ void prep_w(const float* __restrict__ qw, const float* __restrict__ kvw,
                       const float* __restrict__ pw,
                       u16* __restrict__ Wtq, u16* __restrict__ Wtkv,
                       u16* __restrict__ Wph, u16* __restrict__ Wpl) {
  int z = blockIdx.z;
  int N = (z == 1) ? 1024 : 512;
  int col0 = blockIdx.y * 64;
  if (col0 >= N) return;
  int k0 = blockIdx.x * 64;
  const float* W = (z == 0) ? qw : (z == 1) ? kvw : pw;
  __shared__ float T[64][65];
  int t = threadIdx.x;
  int kl = t >> 4, c4 = (t & 15) * 4;
#pragma unroll
  for (int i = 0; i < 4; i++) {
    float4 v = *(const float4*)&W[(size_t)(k0 + kl + i * 16) * N + col0 + c4];
    T[kl + i * 16][c4 + 0] = v.x; T[kl + i * 16][c4 + 1] = v.y;
    T[kl + i * 16][c4 + 2] = v.z; T[kl + i * 16][c4 + 3] = v.w;
  }
  __syncthreads();
#pragma unroll
  for (int p = 0; p < 2; p++) {
    int cl = (t >> 3) + p * 32, k8 = (t & 7) * 8;
    u16 hi[8], lo[8];
#pragma unroll
    for (int j = 0; j < 8; j++) {
      float f = T[k8 + j][cl];
      u16 hv = f2bf(f);
      hi[j] = hv;
      lo[j] = f2bf(f - bf2f(hv));
    }
    size_t o = (size_t)(col0 + cl) * 512 + k0 + k8;
    if (z == 0) *(uint4*)&Wtq[o] = *(const uint4*)hi;
    else if (z == 1) *(uint4*)&Wtkv[o] = *(const uint4*)hi;
    else { *(uint4*)&Wph[o] = *(const uint4*)hi; *(uint4*)&Wpl[o] = *(const uint4*)lo; }
  }
}

// ---------------- MFMA GEMM: merged q+kv projection, 128x128 tile -----------
__global__ __launch_bounds__(256, 4) void gemm_qkv(
    const u16* __restrict__ Xq, const u16* __restrict__ Xkv,
    const u16* __restrict__ Wtq, const u16* __restrict__ Wtkv,
    const float* __restrict__ q_b, const float* __restrict__ kv_b,
    u16* __restrict__ Qb, u16* __restrict__ Kb, u16* __restrict__ Vt) {
  __shared__ __attribute__((aligned(16))) u16 As[128 * 64];
  __shared__ __attribute__((aligned(16))) u16 Bs[128 * 64];
  int t = threadIdx.x, wid = t >> 6, lane = t & 63, lr = lane & 15, lg = lane >> 4;
  int colb = blockIdx.x;
  const u16* A; const u16* Wt; const float* bias; int ch0;
  if (colb < 4) { A = Xq;  Wt = Wtq  + (size_t)colb * 128 * 512;       bias = q_b  + colb * 128;       ch0 = colb * 128; }
  else          { A = Xkv; Wt = Wtkv + (size_t)(colb - 4) * 128 * 512; bias = kv_b + (colb - 4) * 128; ch0 = 512 + (colb - 4) * 128; }
  int row0 = blockIdx.y * 128;
  int wr = wid >> 1, wc = wid & 1;
  f32x4 acc[4][4];
#pragma unroll
  for (int m = 0; m < 4; m++)
#pragma unroll
    for (int n = 0; n < 4; n++) acc[m][n] = (f32x4){0.f, 0.f, 0.f, 0.f};

  for (int k0 = 0; k0 < 512; k0 += 64) {
    __syncthreads();
#pragma unroll
    for (int it = 0; it < 4; it++) {
      int chunk = (wid * 4 + it) * 64 + lane;
      int r = chunk >> 3, sg = chunk & 7;
      gl_lds16(A + (size_t)(row0 + r) * 512 + k0 + ((sg ^ (r & 7)) * 8),
               (char*)As + (size_t)chunk * 16);
    }
#pragma unroll
    for (int it = 0; it < 4; it++) {
      int chunk = (wid * 4 + it) * 64 + lane;
      int r = chunk >> 3, sg = chunk & 7;
      gl_lds16(Wt + (size_t)r * 512 + k0 + ((sg ^ (r & 7)) * 8),
               (char*)Bs + (size_t)chunk * 16);
    }
    __syncthreads();
#pragma unroll
    for (int kk = 0; kk < 2; kk++) {
      bf16x8 bfr[4];
#pragma unroll
      for (int n = 0; n < 4; n++) {
        int col = wc * 64 + n * 16 + lr;
        bfr[n] = *(const bf16x8*)((const char*)Bs + col * 128 + (((kk * 4 + lg) ^ (col & 7)) << 4));
      }
#pragma unroll
      for (int m = 0; m < 4; m++) {
        int row = wr * 64 + m * 16 + lr;
        bf16x8 af = *(const bf16x8*)((const char*)As + row * 128 + (((kk * 4 + lg) ^ (row & 7)) << 4));
#pragma unroll
        for (int n = 0; n < 4; n++)
          acc[m][n] = __builtin_amdgcn_mfma_f32_16x16x32_bf16(af, bfr[n], acc[m][n], 0, 0, 0);
      }
    }
  }
#pragma unroll
  for (int m = 0; m < 4; m++)
#pragma unroll
    for (int n = 0; n < 4; n++) {
      int colg = wc * 64 + n * 16 + lr;
      int ch = ch0 + colg;
      int h = ch / 192, role = (ch >> 6) % 3, d = ch & 63;
      float bs = bias[colg];
      float qsc = (role == 0) ? 0.18033688f : 1.0f;  // 0.125 * log2(e)
      int growb = row0 + wr * 64 + m * 16 + lg * 4;
      int nn = growb >> 10, ssi0 = growb & (S - 1);
      size_t nh = (size_t)(nn * HEADS + h);
      if (role == 2) {
        u16 pk[4];
#pragma unroll
        for (int r = 0; r < 4; r++) pk[r] = f2bf(acc[m][n][r] + bs);
        *(uint2*)&Vt[(nh * DH + d) * S + ssi0] = *(const uint2*)pk;
      } else {
        u16* dst = (role == 0) ? Qb : Kb;
#pragma unroll
        for (int r = 0; r < 4; r++)
          dst[(nh * S + ssi0 + r) * DH + d] = f2bf((acc[m][n][r] + bs) * qsc);
      }
    }
}

// ---------------- MFMA GEMM: proj (Obf bf16 -> out NCHW), W split hi+lo -----
__global__ __launch_bounds__(256) void gemm_proj(
    const u16* __restrict__ Aob, const u16* __restrict__ Wh, const u16* __restrict__ Wl,
    const float* __restrict__ bias, float* __restrict__ out) {
  __shared__ __attribute__((aligned(16))) u16 As[128 * 64];
  __shared__ __attribute__((aligned(16))) u16 Bh[64 * 64];
  __shared__ __attribute__((aligned(16))) u16 Bl[64 * 64];
  int t = threadIdx.x, wid = t >> 6, lane = t & 63, lr = lane & 15, lg = lane >> 4;
  int ch0 = blockIdx.x * 64, row0 = blockIdx.y * 128;
  int wc = wid & 1, wr = wid >> 1;
  f32x4 acc[2][4];
#pragma unroll
  for (int m = 0; m < 2; m++)
#pragma unroll
    for (int n = 0; n < 4; n++) acc[m][n] = (f32x4){0.f, 0.f, 0.f, 0.f};

  for (int k0 = 0; k0 < 512; k0 += 64) {
    __syncthreads();
#pragma unroll
    for (int it = 0; it < 4; it++) {
      int idx = (wid * 4 + it) * 64 + lane;
      int r = idx >> 3, sg = idx & 7;
      gl_lds16(Aob + (size_t)(row0 + r) * 512 + k0 + ((sg ^ (r & 7)) * 8),
               (char*)As + (wid * 4 + it) * 1024);
    }
#pragma unroll
    for (int it = 0; it < 2; it++) {
      int idx = (wid * 2 + it) * 64 + lane;
      int r = idx >> 3, sg = idx & 7;
      size_t go = (size_t)(ch0 + r) * 512 + k0 + ((sg ^ (r & 7)) * 8);
      gl_lds16(Wh + go, (char*)Bh + (wid * 2 + it) * 1024);
      gl_lds16(Wl + go, (char*)Bl + (wid * 2 + it) * 1024);
    }
    __syncthreads();
#pragma unroll
    for (int kk = 0; kk < 2; kk++) {
      bf16x8 ar[4];
#pragma unroll
      for (int n = 0; n < 4; n++) {
        int row = wr * 64 + n * 16 + lr;
        ar[n] = *(const bf16x8*)((const char*)As + row * 128 + (((kk * 4 + lg) ^ (row & 7)) << 4));
      }
#pragma unroll
      for (int m = 0; m < 2; m++) {
        int ch = wc * 32 + m * 16 + lr;
        bf16x8 bh = *(const bf16x8*)((const char*)Bh + ch * 128 + (((kk * 4 + lg) ^ (ch & 7)) << 4));
        bf16x8 bl = *(const bf16x8*)((const char*)Bl + ch * 128 + (((kk * 4 + lg) ^ (ch & 7)) << 4));
#pragma unroll
        for (int n = 0; n < 4; n++) {
          acc[m][n] = __builtin_amdgcn_mfma_f32_16x16x32_bf16(bh, ar[n], acc[m][n], 0, 0, 0);
          acc[m][n] = __builtin_amdgcn_mfma_f32_16x16x32_bf16(bl, ar[n], acc[m][n], 0, 0, 0);
        }
      }
    }
  }
#pragma unroll
  for (int m = 0; m < 2; m++)
#pragma unroll
    for (int n = 0; n < 4; n++) {
      int rowg = row0 + wr * 64 + n * 16 + lr;
      int nn = rowg >> 10, ssi = rowg & (S - 1);
#pragma unroll
      for (int r = 0; r < 4; r++) {
        int ch = ch0 + wc * 32 + m * 16 + lg * 4 + r;
        out[((size_t)nn * C + ch) * S + ssi] = acc[m][n][r] + bias[ch];
      }
    }
}

// ---------------- 32x32 MFMA flash attention, in-register P ------------------
// Wave owns 32 q-rows (q = lane&31). Swapped QK^T: D col=q, row=key(crow).
// P redistributed in-register (cvt_pk + permlane32_swap), PV swapped so O col=q.
// permlane32_swap semantics (HW-confirmed r7): vdst.hi32 <-> vsrc.lo32.
constexpr int KVB = 64;

__global__ __launch_bounds__(256) void attn_kernel(
    const u16* __restrict__ Qbf, const u16* __restrict__ Kbf,
    const u16* __restrict__ Vtb, u16* __restrict__ Obf) {
  __shared__ __attribute__((aligned(16))) u16 Ks[2][KVB * DH];   // [key][d] 8KB
  __shared__ __attribute__((aligned(16))) u16 Vs[2][DH * KVB];   // [d][key] 8KB

  int tid = threadIdx.x;
  int wave = tid >> 6, lane = tid & 63;
  int lq = lane & 31, hi = lane >> 5;
  // XCD-chunked swizzle: 512 blocks, 8 XCDs, 64/chunk
  int w = (blockIdx.x & 7) * 64 + (blockIdx.x >> 3);
  int qt = w & 7, nh = w >> 3;
  const u16* Qg = Qbf + (size_t)nh * S * DH;
  const u16* Kg = Kbf + (size_t)nh * S * DH;
  const u16* Vg = Vtb + (size_t)nh * DH * S;

  // Q fragments (B-operand): lane holds Q[qrow][ks*16 + hi*8 + 0..7]
  int qrow = qt * 128 + wave * 32 + lq;
  bf16x8 qf[4];
#pragma unroll
  for (int ks = 0; ks < 4; ks++)
    qf[ks] = *(const bf16x8*)(Qg + (size_t)qrow * DH + ks * 16 + hi * 8);

  f32x16 oa0 = {}, oa1 = {};
  float m_run = -1e30f, l_run = 0.f;   // per-lane (q = lq), log2 domain

  int e0i = tid, e1i = tid + 256;
  int r0 = e0i >> 3, sg0 = e0i & 7, r1 = e1i >> 3, sg1 = e1i & 7;
  char* kd0 = (char*)&Ks[0][0] + (e0i & ~63) * 16;
  char* kd1 = (char*)&Ks[0][0] + (e1i & ~63) * 16;
  char* vd0 = (char*)&Vs[0][0] + (e0i & ~63) * 16;
  char* vd1 = (char*)&Vs[0][0] + (e1i & ~63) * 16;

#define STAGE(kb, b)                                                             \
  do {                                                                           \
    gl_lds16(Kg + (size_t)((kb) * KVB + r0) * 64 + ((sg0 ^ (r0 & 7)) * 8),       \
             kd0 + (b) * (KVB * DH * 2));                                        \
    gl_lds16(Kg + (size_t)((kb) * KVB + r1) * 64 + ((sg1 ^ (r1 & 7)) * 8),       \
             kd1 + (b) * (KVB * DH * 2));                                        \
    gl_lds16(Vg + (size_t)r0 * S + (kb) * KVB + ((sg0 ^ (r0 & 7)) * 8),          \
             vd0 + (b) * (KVB * DH * 2));                                        \
    gl_lds16(Vg + (size_t)r1 * S + (kb) * KVB + ((sg1 ^ (r1 & 7)) * 8),          \
             vd1 + (b) * (KVB * DH * 2));                                        \
  } while (0)

  STAGE(0, 0);

  for (int kb = 0; kb < S / KVB; kb++) {
    int cur = kb & 1;
    __syncthreads();
    if (kb + 1 < S / KVB) STAGE(kb + 1, cur ^ 1);

    const char* Kc = (const char*)&Ks[cur][0];
    const char* Vc = (const char*)&Vs[cur][0];

    // QK^T swapped: sc_st = K(32key x 64d) . Q(64d x 32q); lane col = q
    f32x16 sc0 = {}, sc1 = {};
#pragma unroll
    for (int ks = 0; ks < 4; ks++) {
      int row0k = lq;            // st=0 key row
      int row1k = 32 + lq;       // st=1 key row
      int sg = ks * 2 + hi;
      bf16x8 kf0 = *(const bf16x8*)(Kc + row0k * 128 + ((sg ^ (lq & 7)) << 4));
      bf16x8 kf1 = *(const bf16x8*)(Kc + row1k * 128 + ((sg ^ (lq & 7)) << 4));
      sc0 = __builtin_amdgcn_mfma_f32_32x32x16_bf16(kf0, qf[ks], sc0, 0, 0, 0);
      sc1 = __builtin_amdgcn_mfma_f32_32x32x16_bf16(kf1, qf[ks], sc1, 0, 0, 0);
    }

    // per-lane row max over the half of the keys this lane holds, + partner
    float pmax = -1e30f;
#pragma unroll
    for (int r = 0; r < 16; r++) pmax = fmaxf(pmax, fmaxf(sc0[r], sc1[r]));
    pmax = fmaxf(pmax, __shfl_xor(pmax, 32));

    // defer-max: 11.5 log2-units = 8 nats
    if (!__all(pmax <= m_run + 11.5f)) {
      float mnew = fmaxf(m_run, pmax);
      float corr = exp2f(m_run - mnew);
      m_run = mnew;
      l_run *= corr;
#pragma unroll
      for (int r = 0; r < 16; r++) { oa0[r] *= corr; oa1[r] *= corr; }
    }

    // exp2 (in place) + partial sum
    float psum = 0.f;
#pragma unroll
    for (int r = 0; r < 16; r++) { sc0[r] = exp2f(sc0[r] - m_run); psum += sc0[r]; }
#pragma unroll
    for (int r = 0; r < 16; r++) { sc1[r] = exp2f(sc1[r] - m_run); psum += sc1[r]; }
    psum += __shfl_xor(psum, 32);
    l_run += psum;

    // pack P to bf16 pairs and exchange halves in-register
    u32 c[16];
    c[0]  = cvtpk(sc0[0],  sc0[1]);  c[1]  = cvtpk(sc0[2],  sc0[3]);
    c[2]  = cvtpk(sc0[4],  sc0[5]);  c[3]  = cvtpk(sc0[6],  sc0[7]);
    c[4]  = cvtpk(sc0[8],  sc0[9]);  c[5]  = cvtpk(sc0[10], sc0[11]);
    c[6]  = cvtpk(sc0[12], sc0[13]); c[7]  = cvtpk(sc0[14], sc0[15]);
    c[8]  = cvtpk(sc1[0],  sc1[1]);  c[9]  = cvtpk(sc1[2],  sc1[3]);
    c[10] = cvtpk(sc1[4],  sc1[5]);  c[11] = cvtpk(sc1[6],  sc1[7]);
    c[12] = cvtpk(sc1[8],  sc1[9]);  c[13] = cvtpk(sc1[10], sc1[11]);
    c[14] = cvtpk(sc1[12], sc1[13]); c[15] = cvtpk(sc1[14], sc1[15]);
    // vdst = even reg (keeps lo half), vsrc = +2 reg (gives its lo to vdst's hi)
    asm("v_permlane32_swap_b32 %0, %1" : "+v"(c[0]),  "+v"(c[2]));
    asm("v_permlane32_swap_b32 %0, %1" : "+v"(c[1]),  "+v"(c[3]));
    asm("v_permlane32_swap_b32 %0, %1" : "+v"(c[4]),  "+v"(c[6]));
    asm("v_permlane32_swap_b32 %0, %1" : "+v"(c[5]),  "+v"(c[7]));
    asm("v_permlane32_swap_b32 %0, %1" : "+v"(c[8]),  "+v"(c[10]));
    asm("v_permlane32_swap_b32 %0, %1" : "+v"(c[9]),  "+v"(c[11]));
    asm("v_permlane32_swap_b32 %0, %1" : "+v"(c[12]), "+v"(c[14]));
    asm("v_permlane32_swap_b32 %0, %1" : "+v"(c[13]), "+v"(c[15]));

    // PV swapped: O(32d x 32q) += Vt(32d x 16k) . P(16k x 32q); lane col = q
#pragma unroll
    for (int kk = 0; kk < 4; kk++) {
      union { u32 u[4]; bf16x8 v; } pu;
      pu.u[0] = c[kk * 4 + 0]; pu.u[1] = c[kk * 4 + 1];
      pu.u[2] = c[kk * 4 + 2]; pu.u[3] = c[kk * 4 + 3];
      int sg = kk * 2 + hi;
      bf16x8 vf0 = *(const bf16x8*)(Vc + lq * 128 + ((sg ^ (lq & 7)) << 4));
      bf16x8 vf1 = *(const bf16x8*)(Vc + (32 + lq) * 128 + ((sg ^ (lq & 7)) << 4));
      oa0 = __builtin_amdgcn_mfma_f32_32x32x16_bf16(vf0, pu.v, oa0, 0, 0, 0);
      oa1 = __builtin_amdgcn_mfma_f32_32x32x16_bf16(vf1, pu.v, oa1, 0, 0, 0);
    }
  }
#undef STAGE

  // epilogue: oaX[r] = O[q=qrow][d = X*32 + (r&3) + 8*(r>>2) + 4*hi], / l
  int n = nh >> 3, h = nh & 7;
  float lf = 1.0f / l_run;
  u16* orow = Obf + ((size_t)n * S + qrow) * C + h * DH;
#pragma unroll
  for (int rq = 0; rq < 4; rq++) {
    int d0 = rq * 8 + 4 * hi;
    uint2 w0, w1;
    w0.x = cvtpk(oa0[rq * 4 + 0] * lf, oa0[rq * 4 + 1] * lf);
    w0.y = cvtpk(oa0[rq * 4 + 2] * lf, oa0[rq * 4 + 3] * lf);
    w1.x = cvtpk(oa1[rq * 4 + 0] * lf, oa1[rq * 4 + 1] * lf);
    w1.y = cvtpk(oa1[rq * 4 + 2] * lf, oa1[rq * 4 + 3] * lf);
    *(uint2*)(orow + d0) = w0;
    *(uint2*)(orow + 32 + d0) = w1;
  }
}

}  // namespace

extern "C" void kernel_launch(void* const* d_in, const int* in_sizes, int n_in,
                              void* d_out, int out_size, void* d_ws, size_t ws_size,
                              hipStream_t stream) {
  const float* x       = (const float*)d_in[0];
  const float* qx      = (const float*)d_in[1];
  const float* q_ln_g  = (const float*)d_in[2];
  const float* q_ln_b  = (const float*)d_in[3];
  const float* q_w     = (const float*)d_in[4];
  const float* q_b     = (const float*)d_in[5];
  const float* kv_ln_g = (const float*)d_in[6];
  const float* kv_ln_b = (const float*)d_in[7];
  const float* kv_w    = (const float*)d_in[8];
  const float* kv_b    = (const float*)d_in[9];
  const float* proj_w  = (const float*)d_in[10];
  const float* proj_b  = (const float*)d_in[11];
  float* out = (float*)d_out;

  u16* u = (u16*)d_ws;
  u16* Xkv  = u;                u += (size_t)RTOT * C;
  u16* Xq   = u;                u += (size_t)RTOT * C;
  u16* Wtq  = u;                u += (size_t)C * C;
  u16* Wtkv = u;                u += (size_t)2 * C * C;
  u16* Wph  = u;                u += (size_t)C * C;
  u16* Wpl  = u;                u += (size_t)C * C;
  u16* Qb   = u;                u += (size_t)NBATCH * HEADS * S * DH;
  u16* Kb   = u;                u += (size_t)NBATCH * HEADS * S * DH;
  u16* Vt   = u;                u += (size_t)NBATCH * HEADS * S * DH;
  u16* Obf  = u;

  hipLaunchKernelGGL(ln_fused, dim3(S / 32, 2 * NBATCH), dim3(256), 0, stream,
                     x, qx, kv_ln_g, kv_ln_b, q_ln_g, q_ln_b, Xkv, Xq);
  hipLaunchKernelGGL(prep_w, dim3(8, 16, 3), dim3(256), 0, stream,
                     q_w, kv_w, proj_w, Wtq, Wtkv, Wph, Wpl);
  hipLaunchKernelGGL(gemm_qkv, dim3(12, RTOT / 128), dim3(256), 0, stream,
                     Xq, Xkv, Wtq, Wtkv, q_b, kv_b, Qb, Kb, Vt);
  hipLaunchKernelGGL(attn_kernel, dim3(512), dim3(256), 0, stream,
                     Qb, Kb, Vt, Obf);
  hipLaunchKernelGGL(gemm_proj, dim3(C / 64, RTOT / 128), dim3(256), 0, stream,
                     Obf, Wph, Wpl, proj_b, out);
}

// Round 9
// 95.729 us; speedup vs baseline: 30.1206x; 1.0293x over previous
//
#include <hip/hip_runtime.h>
#include <math.h>

namespace {

constexpr int S = 1024;
constexpr int C = 512;
constexpr int NBATCH = 8;
constexpr int RTOT = NBATCH * S;  // 8192
constexpr int HEADS = 8;
constexpr int DH = 64;

typedef __attribute__((ext_vector_type(8))) short bf16x8;
typedef __attribute__((ext_vector_type(4))) float f32x4;
typedef __attribute__((ext_vector_type(16))) float f32x16;
typedef unsigned short u16;
typedef unsigned int u32;

__device__ __forceinline__ u16 f2bf(float x) {
  union { float f; u32 u; } v; v.f = x;
  u32 r = v.u + 0x7FFF + ((v.u >> 16) & 1);
  return (u16)(r >> 16);
}
__device__ __forceinline__ float bf2f(u16 b) {
  union { u32 u; float f; } v; v.u = (u32)b << 16; return v.f;
}
__device__ __forceinline__ u32 cvtpk(float a, float b) {  // lo=a, hi=b (RTNE)
  u32 r;
  asm("v_cvt_pk_bf16_f32 %0, %1, %2" : "=v"(r) : "v"(a), "v"(b));
  return r;
}
__device__ __forceinline__ void gl_lds16(const void* g, void* l) {
  auto gp = (const __attribute__((address_space(1))) u32*)g;
  auto lp = (__attribute__((address_space(3))) u32*)l;
  __builtin_amdgcn_global_load_lds(gp, lp, 16, 0, 0);
}

// ---------------- Fused LN: stats + apply + NCHW->(row,c) transpose + bf16 --
__global__ void ln_fused(const float* __restrict__ x, const float* __restrict__ qx,
                         const float* __restrict__ gx, const float* __restrict__ bx,
                         const float* __restrict__ gq, const float* __restrict__ bq,
                         u16* __restrict__ Xkv, u16* __restrict__ Xq) {
  __shared__ float Ssum[8][32], Ssq[8][32];
  __shared__ float mu_s[32], rs_s[32];
  __shared__ float T[32][65];
  int t = threadIdx.x;
  int si0 = blockIdx.x * 32;
  int isq = blockIdx.y & 1, n = blockIdx.y >> 1;
  const float* in = isq ? qx : x;
  const float* g  = isq ? gq : gx;
  const float* be = isq ? bq : bx;
  u16* out = isq ? Xq : Xkv;

  {
    int sl = t & 31, cg = t >> 5;
    const float* p = in + ((size_t)n * C + cg * 64) * S + si0 + sl;
    float s = 0.f, sq = 0.f;
#pragma unroll 8
    for (int c = 0; c < 64; c++) { float v = p[(size_t)c * S]; s += v; sq += v * v; }
    Ssum[cg][sl] = s; Ssq[cg][sl] = sq;
  }
  __syncthreads();
  if (t < 32) {
    float ss = 0.f, q2 = 0.f;
#pragma unroll
    for (int i = 0; i < 8; i++) { ss += Ssum[i][t]; q2 += Ssq[i][t]; }
    float m = ss * (1.0f / C);
    float var = q2 * (1.0f / C) - m * m;
    mu_s[t] = m; rs_s[t] = rsqrtf(var + 1e-5f);
  }
  __syncthreads();

  int si4 = (t & 7) * 4, cl = t >> 3;
  float4 mu4 = *(const float4*)&mu_s[si4];
  float4 rs4 = *(const float4*)&rs_s[si4];
  int wsl = t >> 3, wc8 = (t & 7) * 8;

  for (int c0 = 0; c0 < C; c0 += 64) {
#pragma unroll
    for (int i = 0; i < 2; i++) {
      int c = c0 + cl + i * 32;
      float4 v = *(const float4*)&in[((size_t)n * C + c) * S + si0 + si4];
      float gg = g[c], bb = be[c];
      T[si4 + 0][cl + i * 32] = (v.x - mu4.x) * rs4.x * gg + bb;
      T[si4 + 1][cl + i * 32] = (v.y - mu4.y) * rs4.y * gg + bb;
      T[si4 + 2][cl + i * 32] = (v.z - mu4.z) * rs4.z * gg + bb;
      T[si4 + 3][cl + i * 32] = (v.w - mu4.w) * rs4.w * gg + bb;
    }
    __syncthreads();
    u16 pk[8];
#pragma unroll
    for (int j = 0; j < 8; j++) pk[j] = f2bf(T[wsl][wc8 + j]);
    *(uint4*)&out[((size_t)(n * S + si0 + wsl)) * C + c0 + wc8] = *(const uint4*)pk;
    __syncthreads();
  }
}

// ---------------- Weight prep: W[k][col] -> Wt[col][k] bf16 (+split for proj)
__global__ void prep_w(const float* __restrict__ qw, const float* __restrict__ kvw,
                       const float* __restrict__ pw,
                       u16* __restrict__ Wtq, u16* __restrict__ Wtkv,
                       u16* __restrict__ Wph, u16* __restrict__ Wpl) {
  int z = blockIdx.z;
  int N = (z == 1) ? 1024 : 512;
  int col0 = blockIdx.y * 64;
  if (col0 >= N) return;
  int k0 = blockIdx.x * 64;
  const float* W = (z == 0) ? qw : (z == 1) ? kvw : pw;
  __shared__ float T[64][65];
  int t = threadIdx.x;
  int kl = t >> 4, c4 = (t & 15) * 4;
#pragma unroll
  for (int i = 0; i < 4; i++) {
    float4 v = *(const float4*)&W[(size_t)(k0 + kl + i * 16) * N + col0 + c4];
    T[kl + i * 16][c4 + 0] = v.x; T[kl + i * 16][c4 + 1] = v.y;
    T[kl + i * 16][c4 + 2] = v.z; T[kl + i * 16][c4 + 3] = v.w;
  }
  __syncthreads();
#pragma unroll
  for (int p = 0; p < 2; p++) {
    int cl = (t >> 3) + p * 32, k8 = (t & 7) * 8;
    u16 hi[8], lo[8];
#pragma unroll
    for (int j = 0; j < 8; j++) {
      float f = T[k8 + j][cl];
      u16 hv = f2bf(f);
      hi[j] = hv;
      lo[j] = f2bf(f - bf2f(hv));
    }
    size_t o = (size_t)(col0 + cl) * 512 + k0 + k8;
    if (z == 0) *(uint4*)&Wtq[o] = *(const uint4*)hi;
    else if (z == 1) *(uint4*)&Wtkv[o] = *(const uint4*)hi;
    else { *(uint4*)&Wph[o] = *(const uint4*)hi; *(uint4*)&Wpl[o] = *(const uint4*)lo; }
  }
}

// ---------------- MFMA GEMM: merged q+kv projection, 128x128 tile -----------
__global__ __launch_bounds__(256, 4) void gemm_qkv(
    const u16* __restrict__ Xq, const u16* __restrict__ Xkv,
    const u16* __restrict__ Wtq, const u16* __restrict__ Wtkv,
    const float* __restrict__ q_b, const float* __restrict__ kv_b,
    u16* __restrict__ Qb, u16* __restrict__ Kb, u16* __restrict__ Vt) {
  __shared__ __attribute__((aligned(16))) u16 As[128 * 64];
  __shared__ __attribute__((aligned(16))) u16 Bs[128 * 64];
  int t = threadIdx.x, wid = t >> 6, lane = t & 63, lr = lane & 15, lg = lane >> 4;
  int colb = blockIdx.x;
  const u16* A; const u16* Wt; const float* bias; int ch0;
  if (colb < 4) { A = Xq;  Wt = Wtq  + (size_t)colb * 128 * 512;       bias = q_b  + colb * 128;       ch0 = colb * 128; }
  else          { A = Xkv; Wt = Wtkv + (size_t)(colb - 4) * 128 * 512; bias = kv_b + (colb - 4) * 128; ch0 = 512 + (colb - 4) * 128; }
  int row0 = blockIdx.y * 128;
  int wr = wid >> 1, wc = wid & 1;
  f32x4 acc[4][4];
#pragma unroll
  for (int m = 0; m < 4; m++)
#pragma unroll
    for (int n = 0; n < 4; n++) acc[m][n] = (f32x4){0.f, 0.f, 0.f, 0.f};

  for (int k0 = 0; k0 < 512; k0 += 64) {
    __syncthreads();
#pragma unroll
    for (int it = 0; it < 4; it++) {
      int chunk = (wid * 4 + it) * 64 + lane;
      int r = chunk >> 3, sg = chunk & 7;
      gl_lds16(A + (size_t)(row0 + r) * 512 + k0 + ((sg ^ (r & 7)) * 8),
               (char*)As + (size_t)chunk * 16);
    }
#pragma unroll
    for (int it = 0; it < 4; it++) {
      int chunk = (wid * 4 + it) * 64 + lane;
      int r = chunk >> 3, sg = chunk & 7;
      gl_lds16(Wt + (size_t)r * 512 + k0 + ((sg ^ (r & 7)) * 8),
               (char*)Bs + (size_t)chunk * 16);
    }
    __syncthreads();
#pragma unroll
    for (int kk = 0; kk < 2; kk++) {
      bf16x8 bfr[4];
#pragma unroll
      for (int n = 0; n < 4; n++) {
        int col = wc * 64 + n * 16 + lr;
        bfr[n] = *(const bf16x8*)((const char*)Bs + col * 128 + (((kk * 4 + lg) ^ (col & 7)) << 4));
      }
#pragma unroll
      for (int m = 0; m < 4; m++) {
        int row = wr * 64 + m * 16 + lr;
        bf16x8 af = *(const bf16x8*)((const char*)As + row * 128 + (((kk * 4 + lg) ^ (row & 7)) << 4));
#pragma unroll
        for (int n = 0; n < 4; n++)
          acc[m][n] = __builtin_amdgcn_mfma_f32_16x16x32_bf16(af, bfr[n], acc[m][n], 0, 0, 0);
      }
    }
  }
#pragma unroll
  for (int m = 0; m < 4; m++)
#pragma unroll
    for (int n = 0; n < 4; n++) {
      int colg = wc * 64 + n * 16 + lr;
      int ch = ch0 + colg;
      int h = ch / 192, role = (ch >> 6) % 3, d = ch & 63;
      float bs = bias[colg];
      float qsc = (role == 0) ? 0.18033688f : 1.0f;  // 0.125 * log2(e)
      int growb = row0 + wr * 64 + m * 16 + lg * 4;
      int nn = growb >> 10, ssi0 = growb & (S - 1);
      size_t nh = (size_t)(nn * HEADS + h);
      if (role == 2) {
        u16 pk[4];
#pragma unroll
        for (int r = 0; r < 4; r++) pk[r] = f2bf(acc[m][n][r] + bs);
        *(uint2*)&Vt[(nh * DH + d) * S + ssi0] = *(const uint2*)pk;
      } else {
        u16* dst = (role == 0) ? Qb : Kb;
#pragma unroll
        for (int r = 0; r < 4; r++)
          dst[(nh * S + ssi0 + r) * DH + d] = f2bf((acc[m][n][r] + bs) * qsc);
      }
    }
}

// ---------------- MFMA GEMM: proj (Obf bf16 -> out NCHW), W split hi+lo -----
__global__ __launch_bounds__(256) void gemm_proj(
    const u16* __restrict__ Aob, const u16* __restrict__ Wh, const u16* __restrict__ Wl,
    const float* __restrict__ bias, float* __restrict__ out) {
  __shared__ __attribute__((aligned(16))) u16 As[128 * 64];
  __shared__ __attribute__((aligned(16))) u16 Bh[64 * 64];
  __shared__ __attribute__((aligned(16))) u16 Bl[64 * 64];
  int t = threadIdx.x, wid = t >> 6, lane = t & 63, lr = lane & 15, lg = lane >> 4;
  int ch0 = blockIdx.x * 64, row0 = blockIdx.y * 128;
  int wc = wid & 1, wr = wid >> 1;
  f32x4 acc[2][4];
#pragma unroll
  for (int m = 0; m < 2; m++)
#pragma unroll
    for (int n = 0; n < 4; n++) acc[m][n] = (f32x4){0.f, 0.f, 0.f, 0.f};

  for (int k0 = 0; k0 < 512; k0 += 64) {
    __syncthreads();
#pragma unroll
    for (int it = 0; it < 4; it++) {
      int idx = (wid * 4 + it) * 64 + lane;
      int r = idx >> 3, sg = idx & 7;
      gl_lds16(Aob + (size_t)(row0 + r) * 512 + k0 + ((sg ^ (r & 7)) * 8),
               (char*)As + (wid * 4 + it) * 1024);
    }
#pragma unroll
    for (int it = 0; it < 2; it++) {
      int idx = (wid * 2 + it) * 64 + lane;
      int r = idx >> 3, sg = idx & 7;
      size_t go = (size_t)(ch0 + r) * 512 + k0 + ((sg ^ (r & 7)) * 8);
      gl_lds16(Wh + go, (char*)Bh + (wid * 2 + it) * 1024);
      gl_lds16(Wl + go, (char*)Bl + (wid * 2 + it) * 1024);
    }
    __syncthreads();
#pragma unroll
    for (int kk = 0; kk < 2; kk++) {
      bf16x8 ar[4];
#pragma unroll
      for (int n = 0; n < 4; n++) {
        int row = wr * 64 + n * 16 + lr;
        ar[n] = *(const bf16x8*)((const char*)As + row * 128 + (((kk * 4 + lg) ^ (row & 7)) << 4));
      }
#pragma unroll
      for (int m = 0; m < 2; m++) {
        int ch = wc * 32 + m * 16 + lr;
        bf16x8 bh = *(const bf16x8*)((const char*)Bh + ch * 128 + (((kk * 4 + lg) ^ (ch & 7)) << 4));
        bf16x8 bl = *(const bf16x8*)((const char*)Bl + ch * 128 + (((kk * 4 + lg) ^ (ch & 7)) << 4));
#pragma unroll
        for (int n = 0; n < 4; n++) {
          acc[m][n] = __builtin_amdgcn_mfma_f32_16x16x32_bf16(bh, ar[n], acc[m][n], 0, 0, 0);
          acc[m][n] = __builtin_amdgcn_mfma_f32_16x16x32_bf16(bl, ar[n], acc[m][n], 0, 0, 0);
        }
      }
    }
  }
#pragma unroll
  for (int m = 0; m < 2; m++)
#pragma unroll
    for (int n = 0; n < 4; n++) {
      int rowg = row0 + wr * 64 + n * 16 + lr;
      int nn = rowg >> 10, ssi = rowg & (S - 1);
#pragma unroll
      for (int r = 0; r < 4; r++) {
        int ch = ch0 + wc * 32 + m * 16 + lg * 4 + r;
        out[((size_t)nn * C + ch) * S + ssi] = acc[m][n][r] + bias[ch];
      }
    }
}

// ---------------- 32x32 MFMA flash attention, KV-split, in-register P -------
// Block = 64 q-rows, 4 waves: wave (qg=w&1, kg=w>>1) handles q qg*32+[0,32)
// x keys kg*32+[0,32) of each 64-key tile. O/m/l merged across kg at end.
// permlane32_swap semantics (HW-confirmed r7): vdst.hi-lanes <-> vsrc.lo-lanes.
constexpr int KVB = 64;

__global__ __launch_bounds__(256, 4) void attn_kernel(
    const u16* __restrict__ Qbf, const u16* __restrict__ Kbf,
    const u16* __restrict__ Vtb, u16* __restrict__ Obf) {
  __shared__ __attribute__((aligned(16))) u16 Ks[2][KVB * DH];   // [key][d] 8KB x2
  __shared__ __attribute__((aligned(16))) u16 Vs[2][DH * KVB];   // [d][key] 8KB x2

  int tid = threadIdx.x;
  int wave = tid >> 6, lane = tid & 63;
  int lq = lane & 31, hi = lane >> 5;
  int qg = wave & 1, kg = wave >> 1;
  // XCD-chunked swizzle: 1024 blocks, 8 XCDs, 128/chunk; 16 blocks per nh
  int w = (blockIdx.x & 7) * 128 + (blockIdx.x >> 3);
  int qt = w & 15, nh = w >> 4;
  const u16* Qg = Qbf + (size_t)nh * S * DH;
  const u16* Kg = Kbf + (size_t)nh * S * DH;
  const u16* Vg = Vtb + (size_t)nh * DH * S;

  // Q fragments (B-operand): lane holds Q[qrow][ks*16 + hi*8 + 0..7]
  int qrow = qt * 64 + qg * 32 + lq;
  bf16x8 qf[4];
#pragma unroll
  for (int ks = 0; ks < 4; ks++)
    qf[ks] = *(const bf16x8*)(Qg + (size_t)qrow * DH + ks * 16 + hi * 8);

  f32x16 oa0 = {}, oa1 = {};
  float m_run = -1e30f, l_run = 0.f;   // per-lane (q = lq), log2 domain

  int e0i = tid, e1i = tid + 256;
  int r0 = e0i >> 3, sg0 = e0i & 7, r1 = e1i >> 3, sg1 = e1i & 7;
  char* kd0 = (char*)&Ks[0][0] + (e0i & ~63) * 16;
  char* kd1 = (char*)&Ks[0][0] + (e1i & ~63) * 16;
  char* vd0 = (char*)&Vs[0][0] + (e0i & ~63) * 16;
  char* vd1 = (char*)&Vs[0][0] + (e1i & ~63) * 16;

#define STAGE(kb, b)                                                             \
  do {                                                                           \
    gl_lds16(Kg + (size_t)((kb) * KVB + r0) * 64 + ((sg0 ^ (r0 & 7)) * 8),       \
             kd0 + (b) * (KVB * DH * 2));                                        \
    gl_lds16(Kg + (size_t)((kb) * KVB + r1) * 64 + ((sg1 ^ (r1 & 7)) * 8),       \
             kd1 + (b) * (KVB * DH * 2));                                        \
    gl_lds16(Vg + (size_t)r0 * S + (kb) * KVB + ((sg0 ^ (r0 & 7)) * 8),          \
             vd0 + (b) * (KVB * DH * 2));                                        \
    gl_lds16(Vg + (size_t)r1 * S + (kb) * KVB + ((sg1 ^ (r1 & 7)) * 8),          \
             vd1 + (b) * (KVB * DH * 2));                                        \
  } while (0)

  STAGE(0, 0);

  for (int kb = 0; kb < S / KVB; kb++) {
    int cur = kb & 1;
    __syncthreads();
    if (kb + 1 < S / KVB) STAGE(kb + 1, cur ^ 1);

    const char* Kc = (const char*)&Ks[cur][0];
    const char* Vc = (const char*)&Vs[cur][0];

    // QK^T swapped: sc = K(32key x 64d) . Q(64d x 32q); keys kg*32+[0,32)
    f32x16 sc = {};
#pragma unroll
    for (int ks = 0; ks < 4; ks++) {
      int sg = ks * 2 + hi;
      bf16x8 kf = *(const bf16x8*)(Kc + (kg * 32 + lq) * 128 + ((sg ^ (lq & 7)) << 4));
      sc = __builtin_amdgcn_mfma_f32_32x32x16_bf16(kf, qf[ks], sc, 0, 0, 0);
    }

    // tree max over 16 regs, then partner lane (q shared by hi halves)
    float mx[8];
#pragma unroll
    for (int r = 0; r < 8; r++) mx[r] = fmaxf(sc[2 * r], sc[2 * r + 1]);
#pragma unroll
    for (int r = 0; r < 4; r++) mx[r] = fmaxf(mx[r], mx[r + 4]);
    float pmax = fmaxf(fmaxf(mx[0], mx[1]), fmaxf(mx[2], mx[3]));
    pmax = fmaxf(pmax, __shfl_xor(pmax, 32));

    // defer-max: 11.5 log2-units = 8 nats
    if (!__all(pmax <= m_run + 11.5f)) {
      float mnew = fmaxf(m_run, pmax);
      float corr = exp2f(m_run - mnew);
      m_run = mnew;
      l_run *= corr;
#pragma unroll
      for (int r = 0; r < 16; r++) { oa0[r] *= corr; oa1[r] *= corr; }
    }

    // exp2 (in place) + tree sum
#pragma unroll
    for (int r = 0; r < 16; r++) sc[r] = exp2f(sc[r] - m_run);
    {
      float s8[8];
#pragma unroll
      for (int r = 0; r < 8; r++) s8[r] = sc[2 * r] + sc[2 * r + 1];
#pragma unroll
      for (int r = 0; r < 4; r++) s8[r] += s8[r + 4];
      float psum = (s8[0] + s8[1]) + (s8[2] + s8[3]);
      psum += __shfl_xor(psum, 32);
      l_run += psum;
    }

    // pack P to bf16 pairs and exchange halves in-register
    u32 c[8];
    c[0] = cvtpk(sc[0],  sc[1]);  c[1] = cvtpk(sc[2],  sc[3]);
    c[2] = cvtpk(sc[4],  sc[5]);  c[3] = cvtpk(sc[6],  sc[7]);
    c[4] = cvtpk(sc[8],  sc[9]);  c[5] = cvtpk(sc[10], sc[11]);
    c[6] = cvtpk(sc[12], sc[13]); c[7] = cvtpk(sc[14], sc[15]);
    asm("v_permlane32_swap_b32 %0, %1" : "+v"(c[0]), "+v"(c[2]));
    asm("v_permlane32_swap_b32 %0, %1" : "+v"(c[1]), "+v"(c[3]));
    asm("v_permlane32_swap_b32 %0, %1" : "+v"(c[4]), "+v"(c[6]));
    asm("v_permlane32_swap_b32 %0, %1" : "+v"(c[5]), "+v"(c[7]));

    // PV swapped: O(64d x 32q) += Vt(d x 16k) . P(16k x 32q); keys kg*32+kk*16
#pragma unroll
    for (int kk = 0; kk < 2; kk++) {
      union { u32 u[4]; bf16x8 v; } pu;
      pu.u[0] = c[kk * 4 + 0]; pu.u[1] = c[kk * 4 + 1];
      pu.u[2] = c[kk * 4 + 2]; pu.u[3] = c[kk * 4 + 3];
      int sg = kg * 4 + kk * 2 + hi;
      bf16x8 vf0 = *(const bf16x8*)(Vc + lq * 128 + ((sg ^ (lq & 7)) << 4));
      bf16x8 vf1 = *(const bf16x8*)(Vc + (32 + lq) * 128 + ((sg ^ (lq & 7)) << 4));
      oa0 = __builtin_amdgcn_mfma_f32_32x32x16_bf16(vf0, pu.v, oa0, 0, 0, 0);
      oa1 = __builtin_amdgcn_mfma_f32_32x32x16_bf16(vf1, pu.v, oa1, 0, 0, 0);
    }
  }
#undef STAGE

  // merge kg=1 partials into kg=0 (layout [reg][lane] -> conflict-free)
  __syncthreads();
  float* exO = (float*)&Ks[0][0];   // 2 slots x 32 regs x 64 lanes = 16KB
  float* exS = (float*)&Vs[0][0];
  if (kg) {
    float* o = exO + qg * 2048;
#pragma unroll
    for (int r = 0; r < 16; r++) {
      o[r * 64 + lane] = oa0[r];
      o[(16 + r) * 64 + lane] = oa1[r];
    }
    exS[qg * 128 + lane] = m_run;
    exS[qg * 128 + 64 + lane] = l_run;
  }
  __syncthreads();
  if (!kg) {
    float* o = exO + qg * 2048;
    float m2 = exS[qg * 128 + lane];
    float l2 = exS[qg * 128 + 64 + lane];
    float m = fmaxf(m_run, m2);
    float f0 = exp2f(m_run - m), f2 = exp2f(m2 - m);
    l_run = l_run * f0 + l2 * f2;
#pragma unroll
    for (int r = 0; r < 16; r++) {
      oa0[r] = oa0[r] * f0 + o[r * 64 + lane] * f2;
      oa1[r] = oa1[r] * f0 + o[(16 + r) * 64 + lane] * f2;
    }
    // epilogue: oaX[r] = O[q=qrow][d = X*32 + (r&3) + 8*(r>>2) + 4*hi], / l
    int n = nh >> 3, h = nh & 7;
    float lf = 1.0f / l_run;
    u16* orow = Obf + ((size_t)n * S + qrow) * C + h * DH;
#pragma unroll
    for (int rq = 0; rq < 4; rq++) {
      int d0 = rq * 8 + 4 * hi;
      uint2 w0, w1;
      w0.x = cvtpk(oa0[rq * 4 + 0] * lf, oa0[rq * 4 + 1] * lf);
      w0.y = cvtpk(oa0[rq * 4 + 2] * lf, oa0[rq * 4 + 3] * lf);
      w1.x = cvtpk(oa1[rq * 4 + 0] * lf, oa1[rq * 4 + 1] * lf);
      w1.y = cvtpk(oa1[rq * 4 + 2] * lf, oa1[rq * 4 + 3] * lf);
      *(uint2*)(orow + d0) = w0;
      *(uint2*)(orow + 32 + d0) = w1;
    }
  }
}

}  // namespace

extern "C" void kernel_launch(void* const* d_in, const int* in_sizes, int n_in,
                              void* d_out, int out_size, void* d_ws, size_t ws_size,
                              hipStream_t stream) {
  const float* x       = (const float*)d_in[0];
  const float* qx      = (const float*)d_in[1];
  const float* q_ln_g  = (const float*)d_in[2];
  const float* q_ln_b  = (const float*)d_in[3];
  const float* q_w     = (const float*)d_in[4];
  const float* q_b     = (const float*)d_in[5];
  const float* kv_ln_g = (const float*)d_in[6];
  const float* kv_ln_b = (const float*)d_in[7];
  const float* kv_w    = (const float*)d_in[8];
  const float* kv_b    = (const float*)d_in[9];
  const float* proj_w  = (const float*)d_in[10];
  const float* proj_b  = (const float*)d_in[11];
  float* out = (float*)d_out;

  u16* u = (u16*)d_ws;
  u16* Xkv  = u;                u += (size_t)RTOT * C;
  u16* Xq   = u;                u += (size_t)RTOT * C;
  u16* Wtq  = u;                u += (size_t)C * C;
  u16* Wtkv = u;                u += (size_t)2 * C * C;
  u16* Wph  = u;                u += (size_t)C * C;
  u16* Wpl  = u;                u += (size_t)C * C;
  u16* Qb   = u;                u += (size_t)NBATCH * HEADS * S * DH;
  u16* Kb   = u;                u += (size_t)NBATCH * HEADS * S * DH;
  u16* Vt   = u;                u += (size_t)NBATCH * HEADS * S * DH;
  u16* Obf  = u;

  hipLaunchKernelGGL(ln_fused, dim3(S / 32, 2 * NBATCH), dim3(256), 0, stream,
                     x, qx, kv_ln_g, kv_ln_b, q_ln_g, q_ln_b, Xkv, Xq);
  hipLaunchKernelGGL(prep_w, dim3(8, 16, 3), dim3(256), 0, stream,
                     q_w, kv_w, proj_w, Wtq, Wtkv, Wph, Wpl);
  hipLaunchKernelGGL(gemm_qkv, dim3(12, RTOT / 128), dim3(256), 0, stream,
                     Xq, Xkv, Wtq, Wtkv, q_b, kv_b, Qb, Kb, Vt);
  hipLaunchKernelGGL(attn_kernel, dim3(1024), dim3(256), 0, stream,
                     Qb, Kb, Vt, Obf);
  hipLaunchKernelGGL(gemm_proj, dim3(C / 64, RTOT / 128), dim3(256), 0, stream,
                     Obf, Wph, Wpl, proj_b, out);
}